// Round 2
// baseline (33766.516 us; speedup 1.0000x reference)
//
#include <hip/hip_runtime.h>
#include <hip/hip_cooperative_groups.h>

namespace cg = cooperative_groups;

#define B_   128
#define T_   512
#define KV_  128
#define EMB_ 256
#define H1_  512
#define L_   256
#define NVOC 30
#define NPRED (B_*L_*NVOC)
#define NTHR 512
#define XSS  644   // padded LDS stride (multiple of 4 for float4, %32==4 -> 2-way max)

__device__ __forceinline__ float bf2f(unsigned short u) {
  union { unsigned int u; float f; } c; c.u = ((unsigned int)u) << 16; return c.f;
}
__device__ __forceinline__ unsigned short f2bf(float f) {
  union { float f; unsigned int u; } c; c.f = f;
  unsigned int r = (c.u + 0x7fffu + ((c.u >> 16) & 1u)) >> 16;
  return (unsigned short)r;
}
__device__ __forceinline__ float sigm(float x) { return 1.0f / (1.0f + __expf(-x)); }
__device__ __forceinline__ float tanhh(float x) { return 1.0f - 2.0f / (1.0f + __expf(2.0f * x)); }

struct DecParams {
  const int* y; const int* enc_len;
  const float* W_ih1; const float* W_hh1;
  const float* W_ih2; const float* W_hh2;
  const float* b_ih2; const float* b_hh2;
  const float* table; const unsigned int* keyTp; const unsigned int* value_bf;
  float* H1; float* C1; float* H2; float* C2; float* ctx_state;
  float* qstore; float* ctxstore; float* attn_out;
};

// ---------------------------------------------------------------------------
// prep: build emb-gate table, bf16 transposed key, bf16 value, zero states
// ---------------------------------------------------------------------------
__global__ void prep_kernel(const float* __restrict__ key, const float* __restrict__ value,
                            const float* __restrict__ emb_W, const float* __restrict__ W_ih1,
                            const float* __restrict__ b_ih1, const float* __restrict__ b_hh1,
                            float* __restrict__ table, unsigned int* __restrict__ keyTp,
                            unsigned int* __restrict__ valbf, float* __restrict__ zbase) {
  const int NT_TAB = 31 * 2048;
  const int NT_KEY = B_ * 64 * T_;    // uint entries (d-pairs x t)
  const int NT_VAL = B_ * T_ * 64;    // uint entries
  const int NT_ZER = 2*B_*H1_ + B_*H1_ + 2*B_*KV_ + B_*KV_ + B_*KV_;
  const int total = NT_TAB + NT_KEY + NT_VAL + NT_ZER;
  for (int i = blockIdx.x * blockDim.x + threadIdx.x; i < total;
       i += gridDim.x * blockDim.x) {
    if (i < NT_TAB) {
      int row = i & 2047, v = i >> 11;
      float acc = b_ih1[row] + b_hh1[row];
      if (v < NVOC) {
        const float* e = emb_W + v * EMB_;
        const float* w = W_ih1 + row * 384;
        #pragma unroll 4
        for (int k = 0; k < EMB_; ++k) acc += e[k] * w[k];
      }
      table[v * 2048 + row] = acc;
    } else if (i < NT_TAB + NT_KEY) {
      int j = i - NT_TAB;
      int tt = j & (T_ - 1); int r = j >> 9;
      int dp = r & 63; int b = r >> 6;
      int src = (b * T_ + tt) * KV_ + 2 * dp;
      unsigned int lo = f2bf(key[src]), hi = f2bf(key[src + 1]);
      keyTp[((b * 64 + dp) * T_) + tt] = lo | (hi << 16);
    } else if (i < NT_TAB + NT_KEY + NT_VAL) {
      int j = i - NT_TAB - NT_KEY;          // j = (b*T+t)*64 + d2
      int d2 = j & 63; int r = j >> 6;      // r = b*T+t
      int src = r * KV_ + 2 * d2;
      unsigned int lo = f2bf(value[src]), hi = f2bf(value[src + 1]);
      valbf[j] = lo | (hi << 16);
    } else {
      zbase[i - NT_TAB - NT_KEY - NT_VAL] = 0.0f;
    }
  }
}

// ---------------------------------------------------------------------------
// persistent cooperative kernel, role-split:
//   blocks   0..127 : attention for batch b=blk. K[b] in LDS (128KB),
//                     V[b] in registers (64 VGPR/lane).
//   blocks 128..255 : LSTM slices. ds=(blk-128)&31 (16 h1-dims, 4 h2-dims),
//                     bg=(blk-128)>>5 (32 batch, 2 chunks of 16).
//                     W1 (80KB) + W2 (20KB) slices persistent in LDS.
// 3 grid syncs per step: h1-ready | h2-ready | ctx-ready.
// ---------------------------------------------------------------------------
__global__ void __launch_bounds__(NTHR) decoder_main(DecParams P) {
  __shared__ __align__(16) unsigned char smem[148736];
  cg::grid_group grid = cg::this_grid();
  const int blk = blockIdx.x, tid = threadIdx.x;

  if (blk < B_) {
    // ======================= attention role =======================
    unsigned int* Kl  = (unsigned int*)smem;          // [64 dp][512 t] 128KB
    float* qs    = (float*)(smem + 131072);           // [128]
    float* a_lds = (float*)(smem + 131584);           // [512] unnormalized exp
    float* red   = (float*)(smem + 133632);           // [16]
    float* cbuf  = (float*)(smem + 133760);           // [8][128]
    const int b = blk, w = tid >> 6, l = tid & 63;

    { const uint4* src = (const uint4*)(P.keyTp + b * (64 * T_));
      uint4* dst = (uint4*)Kl;
      for (int i = tid; i < (64 * T_) / 4; i += NTHR) dst[i] = src[i]; }
    unsigned int vreg[64];                            // V[t=64w+i][2l,2l+1]
    { const unsigned int* vb = P.value_bf + b * (T_ * 64) + l;
      #pragma unroll
      for (int i = 0; i < 64; ++i) vreg[i] = vb[(w * 64 + i) * 64]; }
    __syncthreads();
    const int len = P.enc_len[b];
    const float SCALE = 0.08838834764831845f;         // 1/sqrt(128)

    for (int t = 0; t < L_; ++t) {
      const int np = ((t & 1) ^ 1);
      grid.sync();                                    // (phase1 elsewhere)
      grid.sync();                                    // h2 ready
      if (tid < 128) qs[tid] = P.H2[np * (B_ * KV_) + b * KV_ + tid];
      __syncthreads();
      float acc = 0.0f;
      #pragma unroll 8
      for (int dp = 0; dp < 64; ++dp) {
        unsigned int kv = Kl[dp * T_ + tid];
        acc += bf2f((unsigned short)(kv & 0xffffu)) * qs[2 * dp]
             + bf2f((unsigned short)(kv >> 16))     * qs[2 * dp + 1];
      }
      float e = (tid < len) ? acc * SCALE : -8.8388348e7f;   // (-1e9)*scale
      float m = e;
      #pragma unroll
      for (int off = 32; off > 0; off >>= 1) m = fmaxf(m, __shfl_xor(m, off));
      const int lane = tid & 63;
      if (lane == 0) red[w] = m;
      __syncthreads();
      float M = red[0];
      #pragma unroll
      for (int i2 = 1; i2 < 8; ++i2) M = fmaxf(M, red[i2]);
      float pe = __expf(e - M);
      float s = pe;
      #pragma unroll
      for (int off = 32; off > 0; off >>= 1) s += __shfl_xor(s, off);
      if (lane == 0) red[8 + w] = s;
      a_lds[tid] = pe;
      __syncthreads();
      float S = 0.0f;
      #pragma unroll
      for (int i2 = 0; i2 < 8; ++i2) S += red[8 + i2];
      const float invS = 1.0f / S;
      // ctx partial from register-resident V
      float a0 = 0.0f, a1 = 0.0f;
      #pragma unroll
      for (int i = 0; i < 64; ++i) {
        float at = a_lds[w * 64 + i];
        unsigned int v = vreg[i];
        a0 += at * bf2f((unsigned short)(v & 0xffffu));
        a1 += at * bf2f((unsigned short)(v >> 16));
      }
      cbuf[w * 128 + 2 * l]     = a0;
      cbuf[w * 128 + 2 * l + 1] = a1;
      __syncthreads();
      if (tid < 128) {
        float cv = 0.0f;
        #pragma unroll
        for (int ww = 0; ww < 8; ++ww) cv += cbuf[ww * 128 + tid];
        cv *= invS;
        P.ctx_state[b * KV_ + tid] = cv;
        P.ctxstore[(t * B_ + b) * KV_ + tid] = cv;
      }
      if (b == 0) P.attn_out[t * T_ + tid] = pe * invS;
      grid.sync();                                    // ctx ready
    }
  } else {
    // ======================== LSTM role ==========================
    unsigned short* W1l = (unsigned short*)smem;               // 80KB
    unsigned short* W2l = (unsigned short*)(smem + 81920);     // 20KB
    float* xs   = (float*)(smem + 102400);                     // 16*XSS
    float* gbuf = (float*)(smem + 143616);                     // 1280
    const int lb = blk - B_;
    const int ds = lb & 31, bg = lb >> 5;    // bg in 0..3 -> 32 batch

    for (int idx = tid; idx < 640 * 64; idx += NTHR) {
      int r = idx / 640, k = idx - r * 640;
      int grow = (r & 3) * 512 + ds * 16 + (r >> 2);
      float wv = (k < 128) ? P.W_ih1[grow * 384 + 256 + k]
                           : P.W_hh1[grow * 512 + (k - 128)];
      W1l[(k >> 1) * 128 + r * 2 + (k & 1)] = f2bf(wv);
    }
    for (int idx = tid; idx < 640 * 16; idx += NTHR) {
      int r = idx / 640, k = idx - r * 640;
      int grow = (r & 3) * 128 + ds * 4 + (r >> 2);
      float wv = (k < 512) ? P.W_ih2[grow * 512 + k]
                           : P.W_hh2[grow * 128 + (k - 512)];
      W2l[(k >> 1) * 32 + r * 2 + (k & 1)] = f2bf(wv);
    }
    __syncthreads();

    for (int t = 0; t < L_; ++t) {
      const int p = t & 1, np = p ^ 1;

      // ---------------- Phase 1: LSTM1, 2 chunks of 16 batch ----------------
      #pragma unroll 1
      for (int c = 0; c < 2; ++c) {
        const int b0 = bg * 32 + c * 16;
        for (int i = tid; i < 16 * 160; i += NTHR) {
          int bl = i / 160, q = i - bl * 160;
          float4 v = (q < 32)
            ? *(const float4*)&P.ctx_state[(b0 + bl) * KV_ + 4 * q]
            : *(const float4*)&P.H1[p * (B_ * H1_) + (b0 + bl) * H1_ + 4 * q - 128];
          *(float4*)&xs[bl * XSS + 4 * q] = v;
        }
        __syncthreads();
        {
          const int o8 = tid & 255;
          const int bl = o8 & 15, d = o8 >> 4, gh = tid >> 8;
          const int g0 = gh << 1;
          const int ci = (t == 0) ? NVOC : P.y[(b0 + bl) * L_ + (t - 1)];
          const int dglob = ds * 16 + d;
          float acc0 = P.table[ci * 2048 + g0 * 512 + dglob];
          float acc1 = P.table[ci * 2048 + (g0 + 1) * 512 + dglob];
          const float* xrow = xs + bl * XSS;
          const unsigned short* wbase = W1l + (d * 4 + g0) * 2;
          #pragma unroll 4
          for (int k2 = 0; k2 < 320; ++k2) {
            float2 x = *(const float2*)(xrow + 2 * k2);
            ushort4 wv = *(const ushort4*)(wbase + k2 * 128);
            acc0 += x.x * bf2f(wv.x) + x.y * bf2f(wv.y);
            acc1 += x.x * bf2f(wv.z) + x.y * bf2f(wv.w);
          }
          gbuf[o8 * 5 + g0]     = acc0;
          gbuf[o8 * 5 + g0 + 1] = acc1;
        }
        __syncthreads();
        if (tid < 256) {
          const int bl = tid & 15, d = tid >> 4;
          float gi = gbuf[tid * 5 + 0], gf = gbuf[tid * 5 + 1];
          float gg = gbuf[tid * 5 + 2], go = gbuf[tid * 5 + 3];
          const int gidx = (b0 + bl) * H1_ + ds * 16 + d;
          float cc = P.C1[gidx];
          float cn = sigm(gf) * cc + sigm(gi) * tanhh(gg);
          float hn = sigm(go) * tanhh(cn);
          P.C1[gidx] = cn;
          P.H1[np * (B_ * H1_) + gidx] = hn;
        }
        // no extra barrier: next chunk's staging touches xs only; gbuf is
        // re-written only after that chunk's own __syncthreads.
      }
      grid.sync();                                    // h1 ready

      // ---------------- Phase 2: LSTM2, 2 chunks of 16 batch ----------------
      #pragma unroll 1
      for (int c = 0; c < 2; ++c) {
        const int b0 = bg * 32 + c * 16;
        for (int i = tid; i < 16 * 160; i += NTHR) {
          int bl = i / 160, q = i - bl * 160;
          float4 v = (q < 128)
            ? *(const float4*)&P.H1[np * (B_ * H1_) + (b0 + bl) * H1_ + 4 * q]
            : *(const float4*)&P.H2[p * (B_ * KV_) + (b0 + bl) * KV_ + 4 * q - 512];
          *(float4*)&xs[bl * XSS + 4 * q] = v;
        }
        __syncthreads();
        {
          const int o = tid & 255, kh = tid >> 8;
          const int bl = o & 15, r = o >> 4;
          const float* xrow = xs + bl * XSS;
          const unsigned short* wbase = W2l + r * 2;
          float acc = 0.0f;
          const int k2b = kh * 160;
          #pragma unroll 4
          for (int k2i = 0; k2i < 160; ++k2i) {
            int k2 = k2b + k2i;
            float2 x = *(const float2*)(xrow + 2 * k2);
            ushort2 wv = *(const ushort2*)(wbase + k2 * 32);
            acc += x.x * bf2f(wv.x) + x.y * bf2f(wv.y);
          }
          gbuf[o * 2 + kh] = acc;
        }
        __syncthreads();
        if (tid < 64) {
          const int bl = tid & 15, dloc = tid >> 4;
          float g4[4];
          #pragma unroll
          for (int g = 0; g < 4; ++g) {
            const int r = dloc * 4 + g;
            const int o = r * 16 + bl;
            const int grow = g * 128 + ds * 4 + dloc;
            g4[g] = gbuf[o * 2] + gbuf[o * 2 + 1] + P.b_ih2[grow] + P.b_hh2[grow];
          }
          const int gidx = (b0 + bl) * KV_ + ds * 4 + dloc;
          float cc = P.C2[gidx];
          float cn = sigm(g4[1]) * cc + sigm(g4[0]) * tanhh(g4[2]);
          float hn = sigm(g4[3]) * tanhh(cn);
          P.C2[gidx] = cn;
          P.H2[np * (B_ * KV_) + gidx] = hn;
          P.qstore[(t * B_ + (b0 + bl)) * KV_ + ds * 4 + dloc] = hn;
        }
      }
      grid.sync();                                    // h2 ready
      grid.sync();                                    // attention runs here
    }
  }
}

// ---------------------------------------------------------------------------
// tail: predictions[b][t][v] = [q,ctx] @ emb_W.T + out_b   (fully parallel)
// ---------------------------------------------------------------------------
__global__ void pred_tail(const float* __restrict__ qstore, const float* __restrict__ ctxstore,
                          const float* __restrict__ emb_W, const float* __restrict__ out_b,
                          float* __restrict__ preds) {
  int o = blockIdx.x * 256 + threadIdx.x;
  if (o >= NPRED) return;
  int v = o % NVOC;
  int bt = o / NVOC;
  int b = bt >> 8, t = bt & 255;
  const float* q  = qstore   + (t * B_ + b) * KV_;
  const float* cx = ctxstore + (t * B_ + b) * KV_;
  const float* er = emb_W + v * EMB_;
  float acc = out_b[v];
  #pragma unroll 4
  for (int e = 0; e < 128; ++e) acc += q[e] * er[e] + cx[e] * er[128 + e];
  preds[o] = acc;
}

extern "C" void kernel_launch(void* const* d_in, const int* in_sizes, int n_in,
                              void* d_out, int out_size, void* d_ws, size_t ws_size,
                              hipStream_t stream) {
  const float* key    = (const float*)d_in[0];
  const float* value  = (const float*)d_in[1];
  const int*   enclen = (const int*)d_in[2];
  const int*   y      = (const int*)d_in[3];
  const float* emb_W  = (const float*)d_in[4];
  const float* W_ih1  = (const float*)d_in[5];
  const float* W_hh1  = (const float*)d_in[6];
  const float* b_ih1  = (const float*)d_in[7];
  const float* b_hh1  = (const float*)d_in[8];
  const float* W_ih2  = (const float*)d_in[9];
  const float* W_hh2  = (const float*)d_in[10];
  const float* b_ih2  = (const float*)d_in[11];
  const float* b_hh2  = (const float*)d_in[12];
  const float* out_b  = (const float*)d_in[13];

  float* f = (float*)d_ws;
  float* table = f;                        f += 31 * 2048;
  unsigned int* keyTp = (unsigned int*)f;  f += B_ * 64 * T_;
  unsigned int* valbf = (unsigned int*)f;  f += B_ * T_ * 64;
  float* H1   = f; f += 2 * B_ * H1_;      // zero-region starts at H1
  float* C1   = f; f += B_ * H1_;
  float* H2   = f; f += 2 * B_ * KV_;
  float* C2   = f; f += B_ * KV_;
  float* ctxs = f; f += B_ * KV_;
  float* qstore   = f; f += L_ * B_ * KV_;
  float* ctxstore = f; f += L_ * B_ * KV_;

  float* preds    = (float*)d_out;
  float* attn_out = preds + NPRED;

  prep_kernel<<<4096, 256, 0, stream>>>(key, value, emb_W, W_ih1, b_ih1, b_hh1,
                                        table, keyTp, valbf, H1);

  DecParams P{ y, enclen, W_ih1, W_hh1, W_ih2, W_hh2, b_ih2, b_hh2,
               table, keyTp, valbf, H1, C1, H2, C2, ctxs, qstore, ctxstore, attn_out };
  void* kargs[] = { (void*)&P };
  hipLaunchCooperativeKernel((void*)decoder_main, dim3(256), dim3(NTHR), kargs, 0, stream);

  pred_tail<<<(NPRED + 255) / 256, 256, 0, stream>>>(qstore, ctxstore, emb_W, out_b, preds);
}

// Round 3
// 21430.153 us; speedup vs baseline: 1.5757x; 1.5757x over previous
//
#include <hip/hip_runtime.h>
#include <hip/hip_cooperative_groups.h>

namespace cg = cooperative_groups;

#define B_   128
#define T_   512
#define KV_  128
#define EMB_ 256
#define H1_  512
#define L_   256
#define NVOC 30
#define NPRED (B_*L_*NVOC)
#define NTHR 512
#define XSS  644   // padded LDS stride (float4-aligned, %32==4 -> 2-way max)

__device__ __forceinline__ float bf2f(unsigned short u) {
  union { unsigned int u; float f; } c; c.u = ((unsigned int)u) << 16; return c.f;
}
__device__ __forceinline__ unsigned short f2bf(float f) {
  union { float f; unsigned int u; } c; c.f = f;
  unsigned int r = (c.u + 0x7fffu + ((c.u >> 16) & 1u)) >> 16;
  return (unsigned short)r;
}
__device__ __forceinline__ float sigm(float x) { return 1.0f / (1.0f + __expf(-x)); }
__device__ __forceinline__ float tanhh(float x) { return 1.0f - 2.0f / (1.0f + __expf(2.0f * x)); }

struct DecParams {
  const int* y; const int* enc_len;
  const float* W_ih1; const float* W_hh1;
  const float* b_ih2; const float* b_hh2;
  const float* table; const unsigned int* keyTp; const unsigned int* W2T;
  const float* value;
  float* H1; float* ctx_state;
  float* qstore; float* ctxstore; float* attn_out;
  int* flags;   // [0..127] flagH1 per LSTM block, [128..255] flagCtx per batch
};

// ---------------------------------------------------------------------------
// prep: emb-gate table, bf16 transposed key, packed-bf16 W2T, zero state+flags
// ---------------------------------------------------------------------------
__global__ void prep_kernel(const float* __restrict__ key,
                            const float* __restrict__ emb_W, const float* __restrict__ W_ih1,
                            const float* __restrict__ b_ih1, const float* __restrict__ b_hh1,
                            const float* __restrict__ W_ih2, const float* __restrict__ W_hh2,
                            float* __restrict__ table, unsigned int* __restrict__ keyTp,
                            unsigned int* __restrict__ W2T, float* __restrict__ zbase) {
  const int NT_TAB = 31 * 2048;
  const int NT_KEY = B_ * 64 * T_;          // 4194304 uints
  const int NT_W2T = 320 * 512;             // 163840 uints
  const int NT_ZER = 2*B_*H1_ + B_*KV_ + 256;  // H1 dbuf + ctx + flags
  const int total = NT_TAB + NT_KEY + NT_W2T + NT_ZER;
  for (int i = blockIdx.x * blockDim.x + threadIdx.x; i < total;
       i += gridDim.x * blockDim.x) {
    if (i < NT_TAB) {
      int row = i & 2047, v = i >> 11;
      float acc = b_ih1[row] + b_hh1[row];
      if (v < NVOC) {
        const float* e = emb_W + v * EMB_;
        const float* w = W_ih1 + row * 384;
        #pragma unroll 4
        for (int k = 0; k < EMB_; ++k) acc += e[k] * w[k];
      }
      table[v * 2048 + row] = acc;
    } else if (i < NT_TAB + NT_KEY) {
      int j = i - NT_TAB;
      int tt = j & (T_ - 1); int r = j >> 9;
      int dp = r & 63; int b = r >> 6;
      int src = (b * T_ + tt) * KV_ + 2 * dp;
      unsigned int lo = f2bf(key[src]), hi = f2bf(key[src + 1]);
      keyTp[((b * 64 + dp) * T_) + tt] = lo | (hi << 16);
    } else if (i < NT_TAB + NT_KEY + NT_W2T) {
      int j = i - NT_TAB - NT_KEY;
      int r = j & 511, k2 = j >> 9;
      int k0 = 2 * k2;
      float w0, w1;
      if (k0 < 512) { w0 = W_ih2[r * 512 + k0];       w1 = W_ih2[r * 512 + k0 + 1]; }
      else          { w0 = W_hh2[r * 128 + k0 - 512]; w1 = W_hh2[r * 128 + k0 - 511]; }
      W2T[k2 * 512 + r] = (unsigned int)f2bf(w0) | ((unsigned int)f2bf(w1) << 16);
    } else {
      zbase[i - NT_TAB - NT_KEY - NT_W2T] = 0.0f;
    }
  }
}

// ---------------------------------------------------------------------------
// persistent kernel, point-to-point flag pipeline (NO grid.sync):
//   blocks   0..127 ("att") : batch b. LSTM2 (W2T streamed, h2/c2 in LDS) +
//                             attention (K in LDS 128KB, V in 64 VGPR/lane).
//   blocks 128..255 ("lstm"): LSTM1 slice ds=(blk-128)&31 (16 h1-dims),
//                             group g=(blk-128)>>5 (32 batch, 2x16 chunks).
// Flags (agent-scope atomics): flagH1[lb]=t+1 after h1[t] slice written;
//                              flagCtx[b]=t+1 after ctx[t] written.
// att step t  waits flagH1[group] >= t+1.
// lstm step t waits flagCtx[group] >= t  AND  flagH1[group] >= t.
// ---------------------------------------------------------------------------
__global__ void __launch_bounds__(NTHR) decoder_main(DecParams P) {
  __shared__ __align__(16) unsigned char smem[143104];
  const int blk = blockIdx.x, tid = threadIdx.x;

  if (blk < B_) {
    // ======================= att role: LSTM2 + attention =======================
    unsigned int* Kl = (unsigned int*)smem;            // [64 dp][512 t] 128KB
    float* xs2   = (float*)(smem + 131072);            // [640]
    float* h2s   = (float*)(smem + 133632);            // [128]
    float* c2s   = (float*)(smem + 134144);            // [128]
    float* gbuf2 = (float*)(smem + 134656);            // [512]
    float* a_lds = (float*)(smem + 136704);            // [512]
    float* red   = (float*)(smem + 138752);            // [16]
    float* cbuf  = (float*)(smem + 138816);            // [8][128]
    const int b = blk, g32 = (b >> 5) << 5;
    const int w = tid >> 6, l = tid & 63;

    { const uint4* src = (const uint4*)(P.keyTp + (size_t)b * (64 * T_));
      uint4* dst = (uint4*)Kl;
      for (int i = tid; i < (64 * T_) / 4; i += NTHR) dst[i] = src[i]; }
    unsigned int vreg[64];                             // V[t=64w+i][2l,2l+1] bf16x2
    { const float* vb = P.value + (size_t)b * T_ * KV_ + 2 * l;
      #pragma unroll
      for (int i = 0; i < 64; ++i) {
        float2 v = *(const float2*)&vb[(w * 64 + i) * KV_];
        vreg[i] = (unsigned int)f2bf(v.x) | ((unsigned int)f2bf(v.y) << 16);
      } }
    if (tid < 128) { h2s[tid] = 0.0f; c2s[tid] = 0.0f; }
    const float bias2 = P.b_ih2[tid] + P.b_hh2[tid];
    const int len = P.enc_len[b];
    const float SCALE = 0.08838834764831845f;          // 1/sqrt(128)
    __syncthreads();

    for (int t = 0; t < L_; ++t) {
      const int np = (t & 1) ^ 1;
      // ---- wait for h1[t] from the 32 LSTM blocks of this group ----
      if (tid < 64) {
        const int idx = g32 + (tid & 31);
        while (true) {
          int v = __hip_atomic_load(&P.flags[idx], __ATOMIC_RELAXED, __HIP_MEMORY_SCOPE_AGENT);
          if (__all(v >= t + 1)) break;
          __builtin_amdgcn_s_sleep(1);
        }
      }
      __syncthreads();
      __builtin_amdgcn_fence(__ATOMIC_ACQUIRE, "agent");
      // ---- LSTM2: x2 = [h1(512), h2(128)] ----
      xs2[tid] = P.H1[np * (B_ * H1_) + b * H1_ + tid];
      if (tid < 128) xs2[512 + tid] = h2s[tid];
      __syncthreads();
      {
        float acc = bias2;
        const unsigned int* wp = P.W2T + tid;          // [k2][512] coalesced
        #pragma unroll 8
        for (int k2 = 0; k2 < 320; ++k2) {
          unsigned int wv = wp[k2 * 512];
          float2 x = *(const float2*)&xs2[2 * k2];
          acc += x.x * bf2f((unsigned short)(wv & 0xffffu))
               + x.y * bf2f((unsigned short)(wv >> 16));
        }
        gbuf2[tid] = acc;
      }
      __syncthreads();
      if (tid < 128) {
        float gi = gbuf2[tid], gf = gbuf2[128 + tid];
        float gg = gbuf2[256 + tid], go = gbuf2[384 + tid];
        float cc = c2s[tid];
        float cn = sigm(gf) * cc + sigm(gi) * tanhh(gg);
        float hn = sigm(go) * tanhh(cn);
        c2s[tid] = cn; h2s[tid] = hn;
        P.qstore[((size_t)t * B_ + b) * KV_ + tid] = hn;
      }
      __syncthreads();
      // ---- attention: energy / softmax / ctx ----
      float acc = 0.0f;
      #pragma unroll 8
      for (int dp = 0; dp < 64; ++dp) {
        unsigned int kv = Kl[dp * T_ + tid];
        acc += bf2f((unsigned short)(kv & 0xffffu)) * h2s[2 * dp]
             + bf2f((unsigned short)(kv >> 16))     * h2s[2 * dp + 1];
      }
      float e = (tid < len) ? acc * SCALE : -8.8388348e7f;  // (-1e9)*scale
      float m = e;
      #pragma unroll
      for (int off = 32; off > 0; off >>= 1) m = fmaxf(m, __shfl_xor(m, off));
      if (l == 0) red[w] = m;
      __syncthreads();
      float M = red[0];
      #pragma unroll
      for (int i2 = 1; i2 < 8; ++i2) M = fmaxf(M, red[i2]);
      float pe = __expf(e - M);
      float s = pe;
      #pragma unroll
      for (int off = 32; off > 0; off >>= 1) s += __shfl_xor(s, off);
      if (l == 0) red[8 + w] = s;
      a_lds[tid] = pe;
      __syncthreads();
      float S = 0.0f;
      #pragma unroll
      for (int i2 = 0; i2 < 8; ++i2) S += red[8 + i2];
      const float invS = 1.0f / S;
      float a0 = 0.0f, a1 = 0.0f;
      #pragma unroll
      for (int i = 0; i < 64; ++i) {
        float at = a_lds[w * 64 + i];
        unsigned int v = vreg[i];
        a0 += at * bf2f((unsigned short)(v & 0xffffu));
        a1 += at * bf2f((unsigned short)(v >> 16));
      }
      cbuf[w * 128 + 2 * l]     = a0;
      cbuf[w * 128 + 2 * l + 1] = a1;
      __syncthreads();
      if (tid < 128) {
        float cv = 0.0f;
        #pragma unroll
        for (int ww = 0; ww < 8; ++ww) cv += cbuf[ww * 128 + tid];
        cv *= invS;
        P.ctx_state[b * KV_ + tid] = cv;
        P.ctxstore[((size_t)t * B_ + b) * KV_ + tid] = cv;
      }
      if (b == 0) P.attn_out[t * T_ + tid] = pe * invS;
      // ---- publish ctx[t] ----
      __builtin_amdgcn_fence(__ATOMIC_RELEASE, "agent");
      __syncthreads();
      if (tid == 0)
        __hip_atomic_store(&P.flags[128 + b], t + 1, __ATOMIC_RELEASE, __HIP_MEMORY_SCOPE_AGENT);
    }
  } else {
    // ======================== lstm role: LSTM1 slice ==========================
    unsigned short* W1l = (unsigned short*)smem;               // 80KB
    float* xs   = (float*)(smem + 81920);                      // 16*XSS
    float* gbuf = (float*)(smem + 123136);                     // 1280
    float* c1s  = (float*)(smem + 128256);                     // 512
    const int lb = blk - B_;
    const int ds = lb & 31, g32 = (lb >> 5) << 5;

    for (int idx = tid; idx < 640 * 64; idx += NTHR) {
      int r = idx / 640, k = idx - r * 640;
      int grow = (r & 3) * 512 + ds * 16 + (r >> 2);
      float wv = (k < 128) ? P.W_ih1[grow * 384 + 256 + k]
                           : P.W_hh1[grow * 512 + (k - 128)];
      W1l[(k >> 1) * 128 + r * 2 + (k & 1)] = f2bf(wv);
    }
    for (int i = tid; i < 512; i += NTHR) c1s[i] = 0.0f;
    __syncthreads();

    for (int t = 0; t < L_; ++t) {
      const int p = t & 1, np = p ^ 1;
      // ---- wait: ctx[t-1] from att group AND h1[t-1] from group-mates ----
      if (tid < 64) {
        const int idx = (tid < 32) ? (128 + g32 + tid) : (g32 + (tid - 32));
        while (true) {
          int v = __hip_atomic_load(&P.flags[idx], __ATOMIC_RELAXED, __HIP_MEMORY_SCOPE_AGENT);
          if (__all(v >= t)) break;
          __builtin_amdgcn_s_sleep(1);
        }
      }
      __syncthreads();
      __builtin_amdgcn_fence(__ATOMIC_ACQUIRE, "agent");

      #pragma unroll 1
      for (int c = 0; c < 2; ++c) {
        const int b0 = g32 + c * 16;
        for (int i = tid; i < 16 * 160; i += NTHR) {
          int bl = i / 160, q = i - bl * 160;
          float4 v = (q < 32)
            ? *(const float4*)&P.ctx_state[(b0 + bl) * KV_ + 4 * q]
            : *(const float4*)&P.H1[p * (B_ * H1_) + (b0 + bl) * H1_ + 4 * q - 128];
          *(float4*)&xs[bl * XSS + 4 * q] = v;
        }
        __syncthreads();
        {
          const int o8 = tid & 255;
          const int bl = o8 & 15, d = o8 >> 4, gh = tid >> 8;
          const int g0 = gh << 1;
          const int ci = (t == 0) ? NVOC : P.y[(b0 + bl) * L_ + (t - 1)];
          const int dglob = ds * 16 + d;
          float acc0 = P.table[ci * 2048 + g0 * 512 + dglob];
          float acc1 = P.table[ci * 2048 + (g0 + 1) * 512 + dglob];
          const float* xrow = xs + bl * XSS;
          const unsigned short* wbase = W1l + (d * 4 + g0) * 2;
          #pragma unroll 4
          for (int k2 = 0; k2 < 320; ++k2) {
            float2 x = *(const float2*)(xrow + 2 * k2);
            ushort4 wv = *(const ushort4*)(wbase + k2 * 128);
            acc0 += x.x * bf2f(wv.x) + x.y * bf2f(wv.y);
            acc1 += x.x * bf2f(wv.z) + x.y * bf2f(wv.w);
          }
          gbuf[o8 * 5 + g0]     = acc0;
          gbuf[o8 * 5 + g0 + 1] = acc1;
        }
        __syncthreads();
        if (tid < 256) {
          const int bl = tid & 15, d = tid >> 4;
          float gi = gbuf[tid * 5 + 0], gf = gbuf[tid * 5 + 1];
          float gg = gbuf[tid * 5 + 2], go = gbuf[tid * 5 + 3];
          const int gidx = (b0 + bl) * H1_ + ds * 16 + d;
          float cc = c1s[c * 256 + tid];
          float cn = sigm(gf) * cc + sigm(gi) * tanhh(gg);
          float hn = sigm(go) * tanhh(cn);
          c1s[c * 256 + tid] = cn;
          P.H1[np * (B_ * H1_) + gidx] = hn;
        }
        // next chunk's staging only touches xs; gbuf rewritten after its own barrier
      }
      // ---- publish h1[t] slice ----
      __builtin_amdgcn_fence(__ATOMIC_RELEASE, "agent");
      __syncthreads();
      if (tid == 0)
        __hip_atomic_store(&P.flags[lb], t + 1, __ATOMIC_RELEASE, __HIP_MEMORY_SCOPE_AGENT);
    }
  }
}

// ---------------------------------------------------------------------------
// tail: predictions[b][t][v] = [q,ctx] @ emb_W.T + out_b   (fully parallel)
// ---------------------------------------------------------------------------
__global__ void pred_tail(const float* __restrict__ qstore, const float* __restrict__ ctxstore,
                          const float* __restrict__ emb_W, const float* __restrict__ out_b,
                          float* __restrict__ preds) {
  int o = blockIdx.x * 256 + threadIdx.x;
  if (o >= NPRED) return;
  int v = o % NVOC;
  int bt = o / NVOC;
  int b = bt >> 8, t = bt & 255;
  const float* q  = qstore   + ((size_t)t * B_ + b) * KV_;
  const float* cx = ctxstore + ((size_t)t * B_ + b) * KV_;
  const float* er = emb_W + v * EMB_;
  float acc = out_b[v];
  #pragma unroll 4
  for (int e = 0; e < 128; ++e) acc += q[e] * er[e] + cx[e] * er[128 + e];
  preds[o] = acc;
}

extern "C" void kernel_launch(void* const* d_in, const int* in_sizes, int n_in,
                              void* d_out, int out_size, void* d_ws, size_t ws_size,
                              hipStream_t stream) {
  const float* key    = (const float*)d_in[0];
  const float* value  = (const float*)d_in[1];
  const int*   enclen = (const int*)d_in[2];
  const int*   y      = (const int*)d_in[3];
  const float* emb_W  = (const float*)d_in[4];
  const float* W_ih1  = (const float*)d_in[5];
  const float* W_hh1  = (const float*)d_in[6];
  const float* b_ih1  = (const float*)d_in[7];
  const float* b_hh1  = (const float*)d_in[8];
  const float* W_ih2  = (const float*)d_in[9];
  const float* W_hh2  = (const float*)d_in[10];
  const float* b_ih2  = (const float*)d_in[11];
  const float* b_hh2  = (const float*)d_in[12];
  const float* out_b  = (const float*)d_in[13];

  float* f = (float*)d_ws;
  float* table = f;                        f += 31 * 2048;
  unsigned int* keyTp = (unsigned int*)f;  f += B_ * 64 * T_;
  unsigned int* W2T   = (unsigned int*)f;  f += 320 * 512;
  float* H1   = f; f += 2 * B_ * H1_;      // zero-region starts at H1
  float* ctxs = f; f += B_ * KV_;
  int*   flags = (int*)f; f += 256;
  float* qstore   = f; f += L_ * B_ * KV_;
  float* ctxstore = f; f += L_ * B_ * KV_;

  float* preds    = (float*)d_out;
  float* attn_out = preds + NPRED;

  prep_kernel<<<4096, 256, 0, stream>>>(key, emb_W, W_ih1, b_ih1, b_hh1,
                                        W_ih2, W_hh2, table, keyTp, W2T, H1);

  DecParams P{ y, enclen, W_ih1, W_hh1, b_ih2, b_hh2,
               table, keyTp, W2T, value, H1, ctxs, qstore, ctxstore, attn_out, flags };
  void* kargs[] = { (void*)&P };
  hipLaunchCooperativeKernel((void*)decoder_main, dim3(256), dim3(NTHR), kargs, 0, stream);

  pred_tail<<<(NPRED + 255) / 256, 256, 0, stream>>>(qstore, ctxstore, emb_W, out_b, preds);
}

// Round 4
// 11911.504 us; speedup vs baseline: 2.8348x; 1.7991x over previous
//
#include <hip/hip_runtime.h>
#include <hip/hip_cooperative_groups.h>

namespace cg = cooperative_groups;

#define B_   128
#define T_   512
#define KV_  128
#define EMB_ 256
#define H1_  512
#define L_   256
#define NVOC 30
#define NPRED (B_*L_*NVOC)
#define NTHR 512
#define XSS  644   // padded LDS stride (float4-aligned, %32==4 -> 2-way max)

__device__ __forceinline__ float bf2f(unsigned short u) {
  union { unsigned int u; float f; } c; c.u = ((unsigned int)u) << 16; return c.f;
}
__device__ __forceinline__ unsigned short f2bf(float f) {
  union { float f; unsigned int u; } c; c.f = f;
  unsigned int r = (c.u + 0x7fffu + ((c.u >> 16) & 1u)) >> 16;
  return (unsigned short)r;
}
__device__ __forceinline__ float sigm(float x) { return 1.0f / (1.0f + __expf(-x)); }
__device__ __forceinline__ float tanhh(float x) { return 1.0f - 2.0f / (1.0f + __expf(2.0f * x)); }

// agent-scope point-coherent (L3) load/store, no cache-wide fences
__device__ __forceinline__ float aload(const float* p) {
  return __hip_atomic_load((float*)p, __ATOMIC_RELAXED, __HIP_MEMORY_SCOPE_AGENT);
}
__device__ __forceinline__ void astore(float* p, float v) {
  __hip_atomic_store(p, v, __ATOMIC_RELAXED, __HIP_MEMORY_SCOPE_AGENT);
}

struct DecParams {
  const int* y; const int* enc_len;
  const float* W_ih1; const float* W_hh1;
  const float* b_ih2; const float* b_hh2;
  const float* table; const unsigned int* keyTp; const unsigned int* W2T;
  const float* value;
  float* H1; float* ctx_state;
  float* qstore; float* ctxstore; float* attn_out;
  int* flags;   // [0..127] flagH1 per LSTM block, [128..255] flagCtx per batch
};

// ---------------------------------------------------------------------------
// prep: emb-gate table, bf16 transposed key, packed-bf16 W2T, zero state+flags
// ---------------------------------------------------------------------------
__global__ void prep_kernel(const float* __restrict__ key,
                            const float* __restrict__ emb_W, const float* __restrict__ W_ih1,
                            const float* __restrict__ b_ih1, const float* __restrict__ b_hh1,
                            const float* __restrict__ W_ih2, const float* __restrict__ W_hh2,
                            float* __restrict__ table, unsigned int* __restrict__ keyTp,
                            unsigned int* __restrict__ W2T, float* __restrict__ zbase) {
  const int NT_TAB = 31 * 2048;
  const int NT_KEY = B_ * 64 * T_;          // 4194304 uints
  const int NT_W2T = 320 * 512;             // 163840 uints
  const int NT_ZER = 2*B_*H1_ + B_*KV_ + 256;  // H1 dbuf + ctx + flags
  const int total = NT_TAB + NT_KEY + NT_W2T + NT_ZER;
  for (int i = blockIdx.x * blockDim.x + threadIdx.x; i < total;
       i += gridDim.x * blockDim.x) {
    if (i < NT_TAB) {
      int row = i & 2047, v = i >> 11;
      float acc = b_ih1[row] + b_hh1[row];
      if (v < NVOC) {
        const float* e = emb_W + v * EMB_;
        const float* w = W_ih1 + row * 384;
        #pragma unroll 4
        for (int k = 0; k < EMB_; ++k) acc += e[k] * w[k];
      }
      table[v * 2048 + row] = acc;
    } else if (i < NT_TAB + NT_KEY) {
      int j = i - NT_TAB;
      int tt = j & (T_ - 1); int r = j >> 9;
      int dp = r & 63; int b = r >> 6;
      int src = (b * T_ + tt) * KV_ + 2 * dp;
      unsigned int lo = f2bf(key[src]), hi = f2bf(key[src + 1]);
      keyTp[((b * 64 + dp) * T_) + tt] = lo | (hi << 16);
    } else if (i < NT_TAB + NT_KEY + NT_W2T) {
      int j = i - NT_TAB - NT_KEY;
      int r = j & 511, k2 = j >> 9;
      int k0 = 2 * k2;
      float w0, w1;
      if (k0 < 512) { w0 = W_ih2[r * 512 + k0];       w1 = W_ih2[r * 512 + k0 + 1]; }
      else          { w0 = W_hh2[r * 128 + k0 - 512]; w1 = W_hh2[r * 128 + k0 - 511]; }
      W2T[k2 * 512 + r] = (unsigned int)f2bf(w0) | ((unsigned int)f2bf(w1) << 16);
    } else {
      zbase[i - NT_TAB - NT_KEY - NT_W2T] = 0.0f;
    }
  }
}

// ---------------------------------------------------------------------------
// persistent kernel, point-to-point flag pipeline (no grid.sync, NO fences):
//   blocks   0..127 ("att") : batch b. LSTM2 (W2T streamed from L2, h2/c2 in
//                             LDS) + attention (K in LDS 128KB, V in VGPRs).
//   blocks 128..255 ("lstm"): LSTM1 slice ds=(blk-128)&31 (16 h1-dims),
//                             group g=(blk-128)>>5 (32 batch, 2x16 chunks).
// Cross-block data (H1, ctx_state) moves via relaxed agent-scope atomics
// (sc0/sc1, coherent at L3). Producer: data stores -> __syncthreads (compiler
// drains vmcnt before s_barrier) -> relaxed flag store. Consumer: poll flag
// (relaxed agent load) -> relaxed agent data loads. No buffer_wbl2/inv.
// ---------------------------------------------------------------------------
__global__ void __launch_bounds__(NTHR) decoder_main(DecParams P) {
  __shared__ __align__(16) unsigned char smem[143104];
  const int blk = blockIdx.x, tid = threadIdx.x;

  if (blk < B_) {
    // ======================= att role: LSTM2 + attention =======================
    unsigned int* Kl = (unsigned int*)smem;            // [64 dp][512 t] 128KB
    float* xs2   = (float*)(smem + 131072);            // [640]
    float* h2s   = (float*)(smem + 133632);            // [128]
    float* c2s   = (float*)(smem + 134144);            // [128]
    float* gbuf2 = (float*)(smem + 134656);            // [512]
    float* a_lds = (float*)(smem + 136704);            // [512]
    float* red   = (float*)(smem + 138752);            // [16]
    float* cbuf  = (float*)(smem + 138816);            // [8][128]
    const int b = blk, g32 = (b >> 5) << 5;
    const int w = tid >> 6, l = tid & 63;

    { const uint4* src = (const uint4*)(P.keyTp + (size_t)b * (64 * T_));
      uint4* dst = (uint4*)Kl;
      for (int i = tid; i < (64 * T_) / 4; i += NTHR) dst[i] = src[i]; }
    unsigned int vreg[64];                             // V[t=64w+i][2l,2l+1] bf16x2
    { const float* vb = P.value + (size_t)b * T_ * KV_ + 2 * l;
      #pragma unroll
      for (int i = 0; i < 64; ++i) {
        float2 v = *(const float2*)&vb[(w * 64 + i) * KV_];
        vreg[i] = (unsigned int)f2bf(v.x) | ((unsigned int)f2bf(v.y) << 16);
      } }
    if (tid < 128) { h2s[tid] = 0.0f; c2s[tid] = 0.0f; }
    const float bias2 = P.b_ih2[tid] + P.b_hh2[tid];
    const int len = P.enc_len[b];
    const float SCALE = 0.08838834764831845f;          // 1/sqrt(128)
    __syncthreads();

    for (int t = 0; t < L_; ++t) {
      const int np = (t & 1) ^ 1;
      // ---- wait for h1[t] from the 32 LSTM blocks of this group ----
      if (tid < 64) {
        const int idx = g32 + (tid & 31);
        while (true) {
          int v = __hip_atomic_load(&P.flags[idx], __ATOMIC_RELAXED, __HIP_MEMORY_SCOPE_AGENT);
          if (__all(v >= t + 1)) break;
          __builtin_amdgcn_s_sleep(1);
        }
      }
      __syncthreads();
      // ---- LSTM2: x2 = [h1(512), h2(128)] ----
      xs2[tid] = aload(&P.H1[np * (B_ * H1_) + b * H1_ + tid]);
      if (tid < 128) xs2[512 + tid] = h2s[tid];
      __syncthreads();
      {
        float acc = bias2;
        const unsigned int* wp = P.W2T + tid;          // [k2][512] coalesced, L2-hot
        #pragma unroll 8
        for (int k2 = 0; k2 < 320; ++k2) {
          unsigned int wv = wp[k2 * 512];
          float2 x = *(const float2*)&xs2[2 * k2];
          acc += x.x * bf2f((unsigned short)(wv & 0xffffu))
               + x.y * bf2f((unsigned short)(wv >> 16));
        }
        gbuf2[tid] = acc;
      }
      __syncthreads();
      if (tid < 128) {
        float gi = gbuf2[tid], gf = gbuf2[128 + tid];
        float gg = gbuf2[256 + tid], go = gbuf2[384 + tid];
        float cc = c2s[tid];
        float cn = sigm(gf) * cc + sigm(gi) * tanhh(gg);
        float hn = sigm(go) * tanhh(cn);
        c2s[tid] = cn; h2s[tid] = hn;
        P.qstore[((size_t)t * B_ + b) * KV_ + tid] = hn;
      }
      __syncthreads();
      // ---- attention: energy / softmax / ctx ----
      float acc = 0.0f;
      #pragma unroll 8
      for (int dp = 0; dp < 64; ++dp) {
        unsigned int kv = Kl[dp * T_ + tid];
        acc += bf2f((unsigned short)(kv & 0xffffu)) * h2s[2 * dp]
             + bf2f((unsigned short)(kv >> 16))     * h2s[2 * dp + 1];
      }
      float e = (tid < len) ? acc * SCALE : -8.8388348e7f;  // (-1e9)*scale
      float m = e;
      #pragma unroll
      for (int off = 32; off > 0; off >>= 1) m = fmaxf(m, __shfl_xor(m, off));
      if (l == 0) red[w] = m;
      __syncthreads();
      float M = red[0];
      #pragma unroll
      for (int i2 = 1; i2 < 8; ++i2) M = fmaxf(M, red[i2]);
      float pe = __expf(e - M);
      float s = pe;
      #pragma unroll
      for (int off = 32; off > 0; off >>= 1) s += __shfl_xor(s, off);
      if (l == 0) red[8 + w] = s;
      a_lds[tid] = pe;
      __syncthreads();
      float S = 0.0f;
      #pragma unroll
      for (int i2 = 0; i2 < 8; ++i2) S += red[8 + i2];
      const float invS = 1.0f / S;
      float a0 = 0.0f, a1 = 0.0f;
      #pragma unroll
      for (int i = 0; i < 64; ++i) {
        float at = a_lds[w * 64 + i];
        unsigned int v = vreg[i];
        a0 += at * bf2f((unsigned short)(v & 0xffffu));
        a1 += at * bf2f((unsigned short)(v >> 16));
      }
      cbuf[w * 128 + 2 * l]     = a0;
      cbuf[w * 128 + 2 * l + 1] = a1;
      __syncthreads();
      if (tid < 128) {
        float cv = 0.0f;
        #pragma unroll
        for (int ww = 0; ww < 8; ++ww) cv += cbuf[ww * 128 + tid];
        cv *= invS;
        astore(&P.ctx_state[b * KV_ + tid], cv);
        P.ctxstore[((size_t)t * B_ + b) * KV_ + tid] = cv;
      }
      if (b == 0) P.attn_out[t * T_ + tid] = pe * invS;
      // ---- publish ctx[t] (syncthreads drains all waves' stores first) ----
      __syncthreads();
      if (tid == 0)
        __hip_atomic_store(&P.flags[128 + b], t + 1, __ATOMIC_RELAXED, __HIP_MEMORY_SCOPE_AGENT);
    }
  } else {
    // ======================== lstm role: LSTM1 slice ==========================
    unsigned short* W1l = (unsigned short*)smem;               // 80KB
    float* xs   = (float*)(smem + 81920);                      // 16*XSS
    float* gbuf = (float*)(smem + 123136);                     // 1280
    float* c1s  = (float*)(smem + 128256);                     // 512
    const int lb = blk - B_;
    const int ds = lb & 31, g32 = (lb >> 5) << 5;

    for (int idx = tid; idx < 640 * 64; idx += NTHR) {
      int r = idx / 640, k = idx - r * 640;
      int grow = (r & 3) * 512 + ds * 16 + (r >> 2);
      float wv = (k < 128) ? P.W_ih1[grow * 384 + 256 + k]
                           : P.W_hh1[grow * 512 + (k - 128)];
      W1l[(k >> 1) * 128 + r * 2 + (k & 1)] = f2bf(wv);
    }
    for (int i = tid; i < 512; i += NTHR) c1s[i] = 0.0f;
    __syncthreads();

    for (int t = 0; t < L_; ++t) {
      const int p = t & 1, np = p ^ 1;
      // ---- wait: ctx[t-1] from att group AND h1[t-1] from group-mates ----
      if (tid < 64) {
        const int idx = (tid < 32) ? (128 + g32 + tid) : (g32 + (tid - 32));
        while (true) {
          int v = __hip_atomic_load(&P.flags[idx], __ATOMIC_RELAXED, __HIP_MEMORY_SCOPE_AGENT);
          if (__all(v >= t)) break;
          __builtin_amdgcn_s_sleep(1);
        }
      }
      __syncthreads();

      #pragma unroll 1
      for (int c = 0; c < 2; ++c) {
        const int b0 = g32 + c * 16;
        for (int i = tid; i < 16 * 160; i += NTHR) {
          int bl = i / 160, q = i - bl * 160;
          float4 v;
          if (q < 32) {
            const float* src = &P.ctx_state[(b0 + bl) * KV_ + 4 * q];
            v.x = aload(src); v.y = aload(src + 1); v.z = aload(src + 2); v.w = aload(src + 3);
          } else {
            const float* src = &P.H1[p * (B_ * H1_) + (b0 + bl) * H1_ + 4 * q - 128];
            v.x = aload(src); v.y = aload(src + 1); v.z = aload(src + 2); v.w = aload(src + 3);
          }
          *(float4*)&xs[bl * XSS + 4 * q] = v;
        }
        __syncthreads();
        {
          const int o8 = tid & 255;
          const int bl = o8 & 15, d = o8 >> 4, gh = tid >> 8;
          const int g0 = gh << 1;
          const int ci = (t == 0) ? NVOC : P.y[(b0 + bl) * L_ + (t - 1)];
          const int dglob = ds * 16 + d;
          float acc0 = P.table[ci * 2048 + g0 * 512 + dglob];
          float acc1 = P.table[ci * 2048 + (g0 + 1) * 512 + dglob];
          const float* xrow = xs + bl * XSS;
          const unsigned short* wbase = W1l + (d * 4 + g0) * 2;
          #pragma unroll 4
          for (int k2 = 0; k2 < 320; ++k2) {
            float2 x = *(const float2*)(xrow + 2 * k2);
            ushort4 wv = *(const ushort4*)(wbase + k2 * 128);
            acc0 += x.x * bf2f(wv.x) + x.y * bf2f(wv.y);
            acc1 += x.x * bf2f(wv.z) + x.y * bf2f(wv.w);
          }
          gbuf[o8 * 5 + g0]     = acc0;
          gbuf[o8 * 5 + g0 + 1] = acc1;
        }
        __syncthreads();
        if (tid < 256) {
          const int bl = tid & 15, d = tid >> 4;
          float gi = gbuf[tid * 5 + 0], gf = gbuf[tid * 5 + 1];
          float gg = gbuf[tid * 5 + 2], go = gbuf[tid * 5 + 3];
          const int gidx = (b0 + bl) * H1_ + ds * 16 + d;
          float cc = c1s[c * 256 + tid];
          float cn = sigm(gf) * cc + sigm(gi) * tanhh(gg);
          float hn = sigm(go) * tanhh(cn);
          c1s[c * 256 + tid] = cn;
          astore(&P.H1[np * (B_ * H1_) + gidx], hn);
        }
        // next chunk's staging only touches xs; gbuf rewritten after its own barrier
      }
      // ---- publish h1[t] slice (syncthreads drains stores) ----
      __syncthreads();
      if (tid == 0)
        __hip_atomic_store(&P.flags[lb], t + 1, __ATOMIC_RELAXED, __HIP_MEMORY_SCOPE_AGENT);
    }
  }
}

// ---------------------------------------------------------------------------
// tail: predictions[b][t][v] = [q,ctx] @ emb_W.T + out_b   (fully parallel)
// ---------------------------------------------------------------------------
__global__ void pred_tail(const float* __restrict__ qstore, const float* __restrict__ ctxstore,
                          const float* __restrict__ emb_W, const float* __restrict__ out_b,
                          float* __restrict__ preds) {
  int o = blockIdx.x * 256 + threadIdx.x;
  if (o >= NPRED) return;
  int v = o % NVOC;
  int bt = o / NVOC;
  int b = bt >> 8, t = bt & 255;
  const float* q  = qstore   + ((size_t)t * B_ + b) * KV_;
  const float* cx = ctxstore + ((size_t)t * B_ + b) * KV_;
  const float* er = emb_W + v * EMB_;
  float acc = out_b[v];
  #pragma unroll 4
  for (int e = 0; e < 128; ++e) acc += q[e] * er[e] + cx[e] * er[128 + e];
  preds[o] = acc;
}

extern "C" void kernel_launch(void* const* d_in, const int* in_sizes, int n_in,
                              void* d_out, int out_size, void* d_ws, size_t ws_size,
                              hipStream_t stream) {
  const float* key    = (const float*)d_in[0];
  const float* value  = (const float*)d_in[1];
  const int*   enclen = (const int*)d_in[2];
  const int*   y      = (const int*)d_in[3];
  const float* emb_W  = (const float*)d_in[4];
  const float* W_ih1  = (const float*)d_in[5];
  const float* W_hh1  = (const float*)d_in[6];
  const float* b_ih1  = (const float*)d_in[7];
  const float* b_hh1  = (const float*)d_in[8];
  const float* W_ih2  = (const float*)d_in[9];
  const float* W_hh2  = (const float*)d_in[10];
  const float* b_ih2  = (const float*)d_in[11];
  const float* b_hh2  = (const float*)d_in[12];
  const float* out_b  = (const float*)d_in[13];

  float* f = (float*)d_ws;
  float* table = f;                        f += 31 * 2048;
  unsigned int* keyTp = (unsigned int*)f;  f += B_ * 64 * T_;
  unsigned int* W2T   = (unsigned int*)f;  f += 320 * 512;
  float* H1   = f; f += 2 * B_ * H1_;      // zero-region starts at H1
  float* ctxs = f; f += B_ * KV_;
  int*   flags = (int*)f; f += 256;
  float* qstore   = f; f += L_ * B_ * KV_;
  float* ctxstore = f; f += L_ * B_ * KV_;

  float* preds    = (float*)d_out;
  float* attn_out = preds + NPRED;

  prep_kernel<<<4096, 256, 0, stream>>>(key, emb_W, W_ih1, b_ih1, b_hh1,
                                        W_ih2, W_hh2, table, keyTp, W2T, H1);

  DecParams P{ y, enclen, W_ih1, W_hh1, b_ih2, b_hh2,
               table, keyTp, W2T, value, H1, ctxs, qstore, ctxstore, attn_out, flags };
  void* kargs[] = { (void*)&P };
  hipLaunchCooperativeKernel((void*)decoder_main, dim3(256), dim3(NTHR), kargs, 0, stream);

  pred_tail<<<(NPRED + 255) / 256, 256, 0, stream>>>(qstore, ctxstore, emb_W, out_b, preds);
}

// Round 6
// 9594.811 us; speedup vs baseline: 3.5192x; 1.2415x over previous
//
#include <hip/hip_runtime.h>

#define B_   128
#define T_   512
#define KV_  128
#define H1_  512
#define L_   256
#define NVOC 30
#define NPRED (B_*L_*NVOC)
#define NTHR 512

typedef __attribute__((ext_vector_type(8))) short short8v;
typedef __attribute__((ext_vector_type(4))) float float4v;

__device__ __forceinline__ float bf2f(unsigned short u) {
  union { unsigned int u; float f; } c; c.u = ((unsigned int)u) << 16; return c.f;
}
__device__ __forceinline__ unsigned short f2bf(float f) {
  union { float f; unsigned int u; } c; c.f = f;
  unsigned int r = (c.u + 0x7fffu + ((c.u >> 16) & 1u)) >> 16;
  return (unsigned short)r;
}
// pack f32 -> (hi bf16, lo bf16) : x ~= hi + lo with ~2^-18 rel error
__device__ __forceinline__ unsigned int packhl(float x) {
  unsigned short hi = f2bf(x);
  unsigned short lo = f2bf(x - bf2f(hi));
  return (unsigned int)hi | ((unsigned int)lo << 16);
}
__device__ __forceinline__ float sigm(float x) { return 1.0f / (1.0f + __expf(-x)); }
__device__ __forceinline__ float tanhh(float x) { return 1.0f - 2.0f / (1.0f + __expf(2.0f * x)); }

// agent-scope point-coherent (L3) load/store, no cache-wide fences
__device__ __forceinline__ float aloadf(const float* p) {
  return __hip_atomic_load((float*)p, __ATOMIC_RELAXED, __HIP_MEMORY_SCOPE_AGENT);
}
__device__ __forceinline__ unsigned int aloadu(const unsigned int* p) {
  return __hip_atomic_load((unsigned int*)p, __ATOMIC_RELAXED, __HIP_MEMORY_SCOPE_AGENT);
}
__device__ __forceinline__ void astoreu(unsigned int* p, unsigned int v) {
  __hip_atomic_store(p, v, __ATOMIC_RELAXED, __HIP_MEMORY_SCOPE_AGENT);
}

__device__ __forceinline__ float4v mfma16(short8v a, short8v b, float4v c) {
  return __builtin_amdgcn_mfma_f32_16x16x32_bf16(a, b, c, 0, 0, 0);
}

struct DecParams {
  const int* y; const int* enc_len;
  const float* W_ih1; const float* W_hh1;
  const float* W_ih2; const float* W_hh2;
  const float* b_ih2; const float* b_hh2;
  const float* table; const unsigned int* keyTp; const float* value;
  unsigned int* H1hl;   // [2][128][512] (hi,lo) bf16 pair per dim
  unsigned int* H2hl;   // [2][128][128]
  unsigned int* ctx_hl; // [128][128]
  float* qstore; float* ctxstore; float* attn_out;
  int* flags;           // [0..127] h1Flag, [128..255] ctxFlag, [256..383] h2Flag
};

// ---------------------------------------------------------------------------
// prep: emb-gate table, bf16 transposed key, zero state+flags
// ---------------------------------------------------------------------------
__global__ void prep_kernel(const float* __restrict__ key,
                            const float* __restrict__ emb_W, const float* __restrict__ W_ih1,
                            const float* __restrict__ b_ih1, const float* __restrict__ b_hh1,
                            float* __restrict__ table, unsigned int* __restrict__ keyTp,
                            float* __restrict__ zbase) {
  const int NT_TAB = 31 * 2048;
  const int NT_KEY = B_ * 64 * T_;                       // 4194304 uints
  const int NT_ZER = 2*B_*512 + 2*B_*128 + B_*128 + 384; // 180608
  const int total = NT_TAB + NT_KEY + NT_ZER;
  for (int i = blockIdx.x * blockDim.x + threadIdx.x; i < total;
       i += gridDim.x * blockDim.x) {
    if (i < NT_TAB) {
      int row = i & 2047, v = i >> 11;
      float acc = b_ih1[row] + b_hh1[row];
      if (v < NVOC) {
        const float* e = emb_W + v * 256;
        const float* w = W_ih1 + row * 384;
        #pragma unroll 4
        for (int k = 0; k < 256; ++k) acc += e[k] * w[k];
      }
      table[v * 2048 + row] = acc;
    } else if (i < NT_TAB + NT_KEY) {
      int j = i - NT_TAB;
      int tt = j & (T_ - 1); int r = j >> 9;
      int dp = r & 63; int b = r >> 6;
      int src = (b * T_ + tt) * KV_ + 2 * dp;
      unsigned int lo = f2bf(key[src]), hi = f2bf(key[src + 1]);
      keyTp[((b * 64 + dp) * T_) + tt] = lo | (hi << 16);
    } else {
      zbase[i - NT_TAB - NT_KEY] = 0.0f;
    }
  }
}

// ---------------------------------------------------------------------------
// persistent kernel, 3-hop flag pipeline, MFMA LSTMs with hi/lo split state:
//   blocks   0..127 ("att") : batch b. Attention only: K in LDS (128KB),
//                             V in VGPRs, q = hi+lo from H2hl (~f32).
//   blocks 128..255 ("lstm"): group g=(blk-128)>>5 (32 batches), slice
//                             ds=(blk-128)&31 (16 h1-dims, 4 h2-dims).
//                             W1 (83KB) + W2 (21KB) bf16 row-major in LDS.
//     Each GEMV runs TWO MFMA passes over a shared A-tile: hi-pass + lo-pass
//     accumulating into the same f32 acc => state effectively f32 precision;
//     only weights are bf16-rounded (the error budget that passed at 0.0039).
// Hops per step: h1 (lstm all-to-all), h2 (lstm->att), ctx (att->lstm).
// Cross-block data = (hi,lo)-packed uints via relaxed agent atomics at L3.
// Producer: stores -> __syncthreads (drains vmcnt) -> relaxed flag store.
// ---------------------------------------------------------------------------
__global__ void __launch_bounds__(NTHR) decoder_main(DecParams P) {
  __shared__ __align__(16) unsigned char smem[153856];
  const int blk = blockIdx.x, tid = threadIdx.x;
  const int lane = tid & 63, w = tid >> 6;

  if (blk < B_) {
    // ======================= att role: attention only =======================
    unsigned int* Kl = (unsigned int*)smem;            // [64 dp][512 t] 128KB
    float* qs    = (float*)(smem + 131072);            // [128] f32 per dim
    float* a_lds = (float*)(smem + 131584);            // [512]
    float* red   = (float*)(smem + 133632);            // [16]
    float* cbuf  = (float*)(smem + 133760);            // [8][128]
    const int b = blk, g32 = b & ~31;

    { const uint4* src = (const uint4*)(P.keyTp + (size_t)b * (64 * T_));
      uint4* dst = (uint4*)Kl;
      for (int i = tid; i < (64 * T_) / 4; i += NTHR) dst[i] = src[i]; }
    unsigned int vreg[64];                             // V[t=64w+i][2l,2l+1] bf16x2
    { const float* vb = P.value + (size_t)b * T_ * KV_ + 2 * lane;
      #pragma unroll
      for (int i = 0; i < 64; ++i) {
        float2 v = *(const float2*)&vb[(w * 64 + i) * KV_];
        vreg[i] = (unsigned int)f2bf(v.x) | ((unsigned int)f2bf(v.y) << 16);
      } }
    const int len = P.enc_len[b];
    const float SCALE = 0.08838834764831845f;          // 1/sqrt(128)
    __syncthreads();

    for (int t = 0; t < L_; ++t) {
      const int np = (t & 1) ^ 1;
      // ---- wait h2[t] from the 32 lstm blocks of this group ----
      if (tid < 64) {
        const int idx = 256 + g32 + (tid & 31);
        while (true) {
          int v = __hip_atomic_load(&P.flags[idx], __ATOMIC_RELAXED, __HIP_MEMORY_SCOPE_AGENT);
          if (__all(v >= t + 1)) break;
          __builtin_amdgcn_s_sleep(1);
        }
      }
      __syncthreads();
      if (tid < 128) {
        unsigned int u = aloadu(&P.H2hl[np * (B_ * 128) + b * 128 + tid]);
        qs[tid] = bf2f((unsigned short)(u & 0xffffu)) + bf2f((unsigned short)(u >> 16));
      }
      __syncthreads();
      // ---- energy / softmax / ctx ----
      float acc = 0.0f;
      #pragma unroll 8
      for (int dp = 0; dp < 64; ++dp) {
        unsigned int kv = Kl[dp * T_ + tid];
        acc += bf2f((unsigned short)(kv & 0xffffu)) * qs[2 * dp]
             + bf2f((unsigned short)(kv >> 16))     * qs[2 * dp + 1];
      }
      float e = (tid < len) ? acc * SCALE : -8.8388348e7f;  // (-1e9)*scale
      float m = e;
      #pragma unroll
      for (int off = 32; off > 0; off >>= 1) m = fmaxf(m, __shfl_xor(m, off));
      if (lane == 0) red[w] = m;
      __syncthreads();
      float M = red[0];
      #pragma unroll
      for (int i2 = 1; i2 < 8; ++i2) M = fmaxf(M, red[i2]);
      float pe = __expf(e - M);
      float s = pe;
      #pragma unroll
      for (int off = 32; off > 0; off >>= 1) s += __shfl_xor(s, off);
      if (lane == 0) red[8 + w] = s;
      a_lds[tid] = pe;
      __syncthreads();
      float S = 0.0f;
      #pragma unroll
      for (int i2 = 0; i2 < 8; ++i2) S += red[8 + i2];
      const float invS = 1.0f / S;
      float a0 = 0.0f, a1 = 0.0f;
      #pragma unroll
      for (int i = 0; i < 64; ++i) {
        float at = a_lds[w * 64 + i];
        unsigned int v = vreg[i];
        a0 += at * bf2f((unsigned short)(v & 0xffffu));
        a1 += at * bf2f((unsigned short)(v >> 16));
      }
      cbuf[w * 128 + 2 * lane]     = a0;
      cbuf[w * 128 + 2 * lane + 1] = a1;
      __syncthreads();
      if (tid < 128) {
        float cv = 0.0f;
        #pragma unroll
        for (int ww = 0; ww < 8; ++ww) cv += cbuf[ww * 128 + tid];
        cv *= invS;
        astoreu(&P.ctx_hl[b * 128 + tid], packhl(cv));
        P.ctxstore[((size_t)t * B_ + b) * KV_ + tid] = cv;
      }
      if (b == 0) P.attn_out[t * T_ + tid] = pe * invS;
      __syncthreads();                                 // drains stores
      if (tid == 0)
        __hip_atomic_store(&P.flags[128 + b], t + 1, __ATOMIC_RELAXED, __HIP_MEMORY_SCOPE_AGENT);
    }
  } else {
    // ================= lstm role: LSTM1 + LSTM2 slices (MFMA) =================
    unsigned short* W1l = (unsigned short*)smem;             // [64][648] bf16
    unsigned short* W2l = (unsigned short*)(smem + 82944);   // [16][648] bf16
    unsigned short* xA  = (unsigned short*)(smem + 103680);  // [32][648] bf16
    unsigned int*   xAu = (unsigned int*)(smem + 103680);    //  same, uint view [32][324]
    float* gbuf = (float*)(smem + 145152);                   // [32][68] f32
    const int lb = blk - B_;
    const int ds = lb & 31, g32 = (lb >> 5) << 5;

    // pack W1 slice: row r (gate g=r&3, dim ds*16 + (r>>2)), k = [ctx(128), h1(512)]
    for (int idx = tid; idx < 64 * 640; idx += NTHR) {
      int r = idx / 640, k = idx - r * 640;
      int grow = (r & 3) * 512 + ds * 16 + (r >> 2);
      float wv = (k < 128) ? P.W_ih1[grow * 384 + 256 + k]
                           : P.W_hh1[grow * 512 + (k - 128)];
      W1l[r * 648 + k] = f2bf(wv);
    }
    // pack W2 slice: row r (gate g=r&3, dim ds*4 + (r>>2)), k = [h1(512), h2(128)]
    for (int idx = tid; idx < 16 * 640; idx += NTHR) {
      int r = idx / 640, k = idx - r * 640;
      int grow = (r & 3) * 128 + ds * 4 + (r >> 2);
      float wv = (k < 512) ? P.W_ih2[grow * 512 + k]
                           : P.W_hh2[grow * 128 + (k - 512)];
      W2l[r * 648 + k] = f2bf(wv);
    }
    float c1 = 0.0f;                   // cell1: thread (b=tid>>4, d=tid&15)
    float c2 = 0.0f;                   // cell2: thread (b=tid>>2, d=tid&3), tid<128
    float bi2[4];
    {
      const int dloc = tid & 3;
      #pragma unroll
      for (int gq = 0; gq < 4; ++gq) {
        const int grow = gq * 128 + ds * 4 + dloc;
        bi2[gq] = P.b_ih2[grow] + P.b_hh2[grow];
      }
    }
    __syncthreads();

    const int mt = w & 1, nt = w >> 1;
    const int lr = lane & 15, lk = lane >> 4;

    for (int t = 0; t < L_; ++t) {
      const int p = t & 1, np = p ^ 1;
      // ---- A-wait: ctx[t-1] (att) and h1[t-1] (group-mates) ----
      if (tid < 64) {
        const int idx = (tid < 32) ? (128 + g32 + tid) : (g32 + (tid - 32));
        while (true) {
          int v = __hip_atomic_load(&P.flags[idx], __ATOMIC_RELAXED, __HIP_MEMORY_SCOPE_AGENT);
          if (__all(v >= t)) break;
          __builtin_amdgcn_s_sleep(1);
        }
      }
      __syncthreads();

      // ======== LSTM1: x1 = [ctx(128), h1(512)], two passes (hi, lo) ========
      float4v acc1 = {0.0f, 0.0f, 0.0f, 0.0f};
      #pragma unroll 1
      for (int hp = 0; hp < 2; ++hp) {
        for (int i = tid; i < 32 * 320; i += NTHR) {
          int bq = i / 320, kp = i - bq * 320;
          const unsigned int* src = (kp < 64)
            ? &P.ctx_hl[(g32 + bq) * 128 + 2 * kp]
            : &P.H1hl[p * (B_ * 512) + (g32 + bq) * 512 + 2 * (kp - 64)];
          unsigned int u0 = aloadu(src), u1 = aloadu(src + 1);
          xAu[bq * 324 + kp] = hp ? ((u0 >> 16) | (u1 & 0xffff0000u))
                                  : ((u0 & 0xffffu) | (u1 << 16));
        }
        __syncthreads();
        {
          const unsigned short* ap = xA  + (mt * 16 + lr) * 648 + lk * 8;
          const unsigned short* bp = W1l + (nt * 16 + lr) * 648 + lk * 8;
          #pragma unroll
          for (int ks = 0; ks < 20; ++ks)
            acc1 = mfma16(*(const short8v*)(ap + ks * 32),
                          *(const short8v*)(bp + ks * 32), acc1);
        }
        __syncthreads();
      }
      {
        const int m0 = mt * 16 + lk * 4, n = nt * 16 + lr;
        #pragma unroll
        for (int j = 0; j < 4; ++j) gbuf[(m0 + j) * 68 + n] = acc1[j];
      }
      __syncthreads();
      // ---- cell1: gates -> c1/h1; publish h1[t] (hi,lo packed) ----
      {
        const int bq = tid >> 4, d = tid & 15, gb = g32 + bq;
        float4 gv = *(const float4*)&gbuf[bq * 68 + 4 * d];
        const int ci = (t == 0) ? NVOC : P.y[gb * L_ + (t - 1)];
        const int dg = ds * 16 + d;
        const float* tb = P.table + ci * 2048 + dg;
        float gi = gv.x + tb[0];
        float gf = gv.y + tb[512];
        float gg = gv.z + tb[1024];
        float go = gv.w + tb[1536];
        float cn = sigm(gf) * c1 + sigm(gi) * tanhh(gg);
        float hn = sigm(go) * tanhh(cn);
        c1 = cn;
        astoreu(&P.H1hl[np * (B_ * 512) + gb * 512 + dg], packhl(hn));
      }
      __syncthreads();                                 // drains h1 stores
      if (tid == 0)
        __hip_atomic_store(&P.flags[lb], t + 1, __ATOMIC_RELAXED, __HIP_MEMORY_SCOPE_AGENT);
      // ---- D-wait: h1[t] all mates, h2[t-1] all mates ----
      if (tid < 64) {
        const int idx = (tid < 32) ? (g32 + tid) : (256 + g32 + (tid - 32));
        const int thr = (tid < 32) ? (t + 1) : t;
        while (true) {
          int v = __hip_atomic_load(&P.flags[idx], __ATOMIC_RELAXED, __HIP_MEMORY_SCOPE_AGENT);
          if (__all(v >= thr)) break;
          __builtin_amdgcn_s_sleep(1);
        }
      }
      __syncthreads();

      // ======== LSTM2: x2 = [h1(512), h2(128)], two passes (hi, lo) ========
      float4v acc2 = {0.0f, 0.0f, 0.0f, 0.0f};
      #pragma unroll 1
      for (int hp = 0; hp < 2; ++hp) {
        for (int i = tid; i < 32 * 320; i += NTHR) {
          int bq = i / 320, kp = i - bq * 320;
          const unsigned int* src = (kp < 256)
            ? &P.H1hl[np * (B_ * 512) + (g32 + bq) * 512 + 2 * kp]
            : &P.H2hl[p * (B_ * 128) + (g32 + bq) * 128 + 2 * (kp - 256)];
          unsigned int u0 = aloadu(src), u1 = aloadu(src + 1);
          xAu[bq * 324 + kp] = hp ? ((u0 >> 16) | (u1 & 0xffff0000u))
                                  : ((u0 & 0xffffu) | (u1 << 16));
        }
        __syncthreads();
        if (w < 2) {
          const unsigned short* ap = xA  + (w * 16 + lr) * 648 + lk * 8;
          const unsigned short* bp = W2l + lr * 648 + lk * 8;
          #pragma unroll
          for (int ks = 0; ks < 20; ++ks)
            acc2 = mfma16(*(const short8v*)(ap + ks * 32),
                          *(const short8v*)(bp + ks * 32), acc2);
        }
        __syncthreads();
      }
      if (w < 2) {
        const int m0 = w * 16 + lk * 4, n = lr;
        #pragma unroll
        for (int j = 0; j < 4; ++j) gbuf[(m0 + j) * 68 + n] = acc2[j];
      }
      __syncthreads();
      // ---- cell2: gates -> c2/h2; publish h2[t] (hi,lo); qstore f32 ----
      if (tid < 128) {
        const int bq = tid >> 2, dloc = tid & 3, gb = g32 + bq;
        float4 gv = *(const float4*)&gbuf[bq * 68 + 4 * dloc];
        float gi = gv.x + bi2[0];
        float gf = gv.y + bi2[1];
        float gg = gv.z + bi2[2];
        float go = gv.w + bi2[3];
        float cn = sigm(gf) * c2 + sigm(gi) * tanhh(gg);
        float hn = sigm(go) * tanhh(cn);
        c2 = cn;
        P.qstore[((size_t)t * B_ + gb) * KV_ + ds * 4 + dloc] = hn;
        astoreu(&P.H2hl[np * (B_ * 128) + gb * 128 + ds * 4 + dloc], packhl(hn));
      }
      __syncthreads();                                 // drains h2 stores
      if (tid == 0)
        __hip_atomic_store(&P.flags[256 + lb], t + 1, __ATOMIC_RELAXED, __HIP_MEMORY_SCOPE_AGENT);
    }
  }
}

// ---------------------------------------------------------------------------
// tail: predictions[b][t][v] = [q,ctx] @ emb_W.T + out_b   (fully parallel)
// ---------------------------------------------------------------------------
__global__ void pred_tail(const float* __restrict__ qstore, const float* __restrict__ ctxstore,
                          const float* __restrict__ emb_W, const float* __restrict__ out_b,
                          float* __restrict__ preds) {
  int o = blockIdx.x * 256 + threadIdx.x;
  if (o >= NPRED) return;
  int v = o % NVOC;
  int bt = o / NVOC;
  int b = bt >> 8, t = bt & 255;
  const float* q  = qstore   + ((size_t)t * B_ + b) * KV_;
  const float* cx = ctxstore + ((size_t)t * B_ + b) * KV_;
  const float* er = emb_W + v * 256;
  float acc = out_b[v];
  #pragma unroll 4
  for (int e = 0; e < 128; ++e) acc += q[e] * er[e] + cx[e] * er[128 + e];
  preds[o] = acc;
}

extern "C" void kernel_launch(void* const* d_in, const int* in_sizes, int n_in,
                              void* d_out, int out_size, void* d_ws, size_t ws_size,
                              hipStream_t stream) {
  const float* key    = (const float*)d_in[0];
  const float* value  = (const float*)d_in[1];
  const int*   enclen = (const int*)d_in[2];
  const int*   y      = (const int*)d_in[3];
  const float* emb_W  = (const float*)d_in[4];
  const float* W_ih1  = (const float*)d_in[5];
  const float* W_hh1  = (const float*)d_in[6];
  const float* b_ih1  = (const float*)d_in[7];
  const float* b_hh1  = (const float*)d_in[8];
  const float* W_ih2  = (const float*)d_in[9];
  const float* W_hh2  = (const float*)d_in[10];
  const float* b_ih2  = (const float*)d_in[11];
  const float* b_hh2  = (const float*)d_in[12];
  const float* out_b  = (const float*)d_in[13];

  float* f = (float*)d_ws;
  float* table = f;                        f += 31 * 2048;
  unsigned int* keyTp = (unsigned int*)f;  f += B_ * 64 * T_;
  unsigned int* H1hl = (unsigned int*)f;   f += 2 * B_ * 512;   // zero-region start
  unsigned int* H2hl = (unsigned int*)f;   f += 2 * B_ * 128;
  unsigned int* ctx_hl = (unsigned int*)f; f += B_ * 128;
  int*   flags = (int*)f;                  f += 384;
  float* qstore   = f;                     f += (size_t)L_ * B_ * KV_;
  float* ctxstore = f;                     f += (size_t)L_ * B_ * KV_;

  float* preds    = (float*)d_out;
  float* attn_out = preds + NPRED;

  prep_kernel<<<4096, 256, 0, stream>>>(key, emb_W, W_ih1, b_ih1, b_hh1,
                                        table, keyTp, (float*)H1hl);

  DecParams P{ y, enclen, W_ih1, W_hh1, W_ih2, W_hh2, b_ih2, b_hh2,
               table, keyTp, value, H1hl, H2hl, ctx_hl, qstore, ctxstore, attn_out, flags };
  void* kargs[] = { (void*)&P };
  hipLaunchCooperativeKernel((void*)decoder_main, dim3(256), dim3(NTHR), kargs, 0, stream);

  pred_tail<<<(NPRED + 255) / 256, 256, 0, stream>>>(qstore, ctxstore, emb_W, out_b, preds);
}

// Round 7
// 7286.083 us; speedup vs baseline: 4.6344x; 1.3169x over previous
//
#include <hip/hip_runtime.h>

#define B_   128
#define T_   512
#define KV_  128
#define H1_  512
#define L_   256
#define NVOC 30
#define NPRED (B_*L_*NVOC)
#define NTHR 512

typedef __attribute__((ext_vector_type(8))) short short8v;
typedef __attribute__((ext_vector_type(4))) float float4v;

__device__ __forceinline__ float bf2f(unsigned short u) {
  union { unsigned int u; float f; } c; c.u = ((unsigned int)u) << 16; return c.f;
}
__device__ __forceinline__ unsigned short f2bf(float f) {
  union { float f; unsigned int u; } c; c.f = f;
  unsigned int r = (c.u + 0x7fffu + ((c.u >> 16) & 1u)) >> 16;
  return (unsigned short)r;
}
__device__ __forceinline__ float sigm(float x) { return 1.0f / (1.0f + __expf(-x)); }
__device__ __forceinline__ float tanhh(float x) { return 1.0f - 2.0f / (1.0f + __expf(2.0f * x)); }

// agent-scope point-coherent load/store (no cache-wide fences)
__device__ __forceinline__ unsigned int aloadu(const unsigned int* p) {
  return __hip_atomic_load((unsigned int*)p, __ATOMIC_RELAXED, __HIP_MEMORY_SCOPE_AGENT);
}
__device__ __forceinline__ void astoreu(unsigned int* p, unsigned int v) {
  __hip_atomic_store(p, v, __ATOMIC_RELAXED, __HIP_MEMORY_SCOPE_AGENT);
}
__device__ __forceinline__ float4v mfma16(short8v a, short8v b, float4v c) {
  return __builtin_amdgcn_mfma_f32_16x16x32_bf16(a, b, c, 0, 0, 0);
}

struct DecParams {
  const int* y; const int* enc_len;
  const float* W_ih1; const float* W_hh1;
  const float* W_ih2; const float* W_hh2;
  const float* b_ih2; const float* b_hh2;
  const float* table; const unsigned int* keyTp; const float* value;
  unsigned int* H1hi; unsigned int* H1lo;   // [2][128][256] bf16x2 (dim pairs)
  unsigned int* H2hi; unsigned int* H2lo;   // [2][128][64]
  unsigned int* CTXhi; unsigned int* CTXlo; // [128][64]
  float* qstore; float* ctxstore; float* attn_out;
  int* flags;   // [0..127] h1Flag(lb), [128..255] ctxFlag(b), [256..383] h2Flag(lb)
};

// ---------------------------------------------------------------------------
// prep: emb-gate table, bf16 transposed key, zero state+flags
// ---------------------------------------------------------------------------
__global__ void prep_kernel(const float* __restrict__ key,
                            const float* __restrict__ emb_W, const float* __restrict__ W_ih1,
                            const float* __restrict__ b_ih1, const float* __restrict__ b_hh1,
                            float* __restrict__ table, unsigned int* __restrict__ keyTp,
                            float* __restrict__ zbase) {
  const int NT_TAB = 31 * 2048;
  const int NT_KEY = B_ * 64 * T_;                       // 4194304 uints
  const int NT_ZER = 2*(2*B_*256) + 2*(2*B_*64) + 2*(B_*64) + 384;  // 180608
  const int total = NT_TAB + NT_KEY + NT_ZER;
  for (int i = blockIdx.x * blockDim.x + threadIdx.x; i < total;
       i += gridDim.x * blockDim.x) {
    if (i < NT_TAB) {
      int row = i & 2047, v = i >> 11;
      float acc = b_ih1[row] + b_hh1[row];
      if (v < NVOC) {
        const float* e = emb_W + v * 256;
        const float* w = W_ih1 + row * 384;
        #pragma unroll 4
        for (int k = 0; k < 256; ++k) acc += e[k] * w[k];
      }
      table[v * 2048 + row] = acc;
    } else if (i < NT_TAB + NT_KEY) {
      int j = i - NT_TAB;
      int tt = j & (T_ - 1); int r = j >> 9;
      int dp = r & 63; int b = r >> 6;
      int src = (b * T_ + tt) * KV_ + 2 * dp;
      unsigned int lo = f2bf(key[src]), hi = f2bf(key[src + 1]);
      keyTp[((b * 64 + dp) * T_) + tt] = lo | (hi << 16);
    } else {
      zbase[i - NT_TAB - NT_KEY] = 0.0f;
    }
  }
}

// ---------------------------------------------------------------------------
// persistent kernel, split-K flag pipeline, MFMA LSTMs, hi/lo state arrays:
//   blocks   0..127 ("att") : batch b. Attention only (K LDS, V VGPRs).
//   blocks 128..255 ("lstm"): group g32, slice ds. W1/W2 bf16 in LDS.
// Per step t in lstm blocks:
//   G1h  = W1[:,128:640] @ h1[t-1]   (LDS tile, OFF critical path)
//   G2s  = W2[:,512:640] @ h2[t-1]   (register A-frags, off path)
//   G1c += W1[:,  0:128] @ ctx[t-1]  (register A-frags, ON critical path)
//   cell1 -> publish h1[t] -> G2h = W2[:,0:512] @ h1[t] -> cell2 -> h2[t]
// State crosses blocks as separate hi/lo bf16-pair arrays (halved traffic).
// Producer pattern: stores -> __syncthreads (drains vmcnt) -> flag store.
// ---------------------------------------------------------------------------
__global__ void __launch_bounds__(NTHR) decoder_main(DecParams P) {
  __shared__ __align__(16) unsigned char smem[145664];
  const int blk = blockIdx.x, tid = threadIdx.x;
  const int lane = tid & 63, w = tid >> 6;

  if (blk < B_) {
    // ======================= att role: attention only =======================
    unsigned int* Kl = (unsigned int*)smem;            // [64 dp][512 t] 128KB
    float* qs    = (float*)(smem + 131072);            // [128]
    float* a_lds = (float*)(smem + 131584);            // [512]
    float* red   = (float*)(smem + 133632);            // [16]
    float* cbuf  = (float*)(smem + 133760);            // [8][128]
    const int b = blk, g32 = b & ~31;

    { const uint4* src = (const uint4*)(P.keyTp + (size_t)b * (64 * T_));
      uint4* dst = (uint4*)Kl;
      for (int i = tid; i < (64 * T_) / 4; i += NTHR) dst[i] = src[i]; }
    unsigned int vreg[64];                             // V[t=64w+i][2l,2l+1] bf16x2
    { const float* vb = P.value + (size_t)b * T_ * KV_ + 2 * lane;
      #pragma unroll
      for (int i = 0; i < 64; ++i) {
        float2 v = *(const float2*)&vb[(w * 64 + i) * KV_];
        vreg[i] = (unsigned int)f2bf(v.x) | ((unsigned int)f2bf(v.y) << 16);
      } }
    const int len = P.enc_len[b];
    const float SCALE = 0.08838834764831845f;          // 1/sqrt(128)
    __syncthreads();

    for (int t = 0; t < L_; ++t) {
      const int np = (t & 1) ^ 1;
      // ---- wait h2[t] ----
      if (tid < 64) {
        const int idx = 256 + g32 + (tid & 31);
        while (true) {
          int v = __hip_atomic_load(&P.flags[idx], __ATOMIC_RELAXED, __HIP_MEMORY_SCOPE_AGENT);
          if (__all(v >= t + 1)) break;
          __builtin_amdgcn_s_sleep(1);
        }
      }
      __syncthreads();
      if (tid < 64) {
        unsigned int uh = aloadu(&P.H2hi[np * (B_ * 64) + b * 64 + tid]);
        unsigned int ul = aloadu(&P.H2lo[np * (B_ * 64) + b * 64 + tid]);
        qs[2 * tid]     = bf2f((unsigned short)(uh & 0xffffu)) + bf2f((unsigned short)(ul & 0xffffu));
        qs[2 * tid + 1] = bf2f((unsigned short)(uh >> 16))     + bf2f((unsigned short)(ul >> 16));
      }
      __syncthreads();
      // ---- energy / softmax / ctx ----
      float acc = 0.0f;
      #pragma unroll 8
      for (int dp = 0; dp < 64; ++dp) {
        unsigned int kv = Kl[dp * T_ + tid];
        acc += bf2f((unsigned short)(kv & 0xffffu)) * qs[2 * dp]
             + bf2f((unsigned short)(kv >> 16))     * qs[2 * dp + 1];
      }
      float e = (tid < len) ? acc * SCALE : -8.8388348e7f;  // (-1e9)*scale
      float m = e;
      #pragma unroll
      for (int off = 32; off > 0; off >>= 1) m = fmaxf(m, __shfl_xor(m, off));
      if (lane == 0) red[w] = m;
      __syncthreads();
      float M = red[0];
      #pragma unroll
      for (int i2 = 1; i2 < 8; ++i2) M = fmaxf(M, red[i2]);
      float pe = __expf(e - M);
      float s = pe;
      #pragma unroll
      for (int off = 32; off > 0; off >>= 1) s += __shfl_xor(s, off);
      if (lane == 0) red[8 + w] = s;
      a_lds[tid] = pe;
      __syncthreads();
      float S = 0.0f;
      #pragma unroll
      for (int i2 = 0; i2 < 8; ++i2) S += red[8 + i2];
      const float invS = 1.0f / S;
      float a0 = 0.0f, a1 = 0.0f;
      #pragma unroll
      for (int i = 0; i < 64; ++i) {
        float at = a_lds[w * 64 + i];
        unsigned int v = vreg[i];
        a0 += at * bf2f((unsigned short)(v & 0xffffu));
        a1 += at * bf2f((unsigned short)(v >> 16));
      }
      cbuf[w * 128 + 2 * lane]     = a0;
      cbuf[w * 128 + 2 * lane + 1] = a1;
      __syncthreads();
      if (tid < 128) {
        float cv = 0.0f;
        #pragma unroll
        for (int ww = 0; ww < 8; ++ww) cv += cbuf[ww * 128 + tid];
        cv *= invS;
        P.ctxstore[((size_t)t * B_ + b) * KV_ + tid] = cv;
        float cvp = __shfl_xor(cv, 1);
        if (!(tid & 1)) {
          unsigned short h0 = f2bf(cv),  l0 = f2bf(cv - bf2f(h0));
          unsigned short h1v = f2bf(cvp), l1 = f2bf(cvp - bf2f(h1v));
          astoreu(&P.CTXhi[b * 64 + (tid >> 1)], (unsigned int)h0 | ((unsigned int)h1v << 16));
          astoreu(&P.CTXlo[b * 64 + (tid >> 1)], (unsigned int)l0 | ((unsigned int)l1 << 16));
        }
      }
      if (b == 0) P.attn_out[t * T_ + tid] = pe * invS;
      __syncthreads();                                 // drain stores
      if (tid == 0)
        __hip_atomic_store(&P.flags[128 + b], t + 1, __ATOMIC_RELAXED, __HIP_MEMORY_SCOPE_AGENT);
    }
  } else {
    // ================= lstm role: LSTM1 + LSTM2 slices (MFMA) =================
    unsigned short* W1l = (unsigned short*)smem;             // [64][648] bf16
    unsigned short* W2l = (unsigned short*)(smem + 82944);   // [16][648] bf16
    unsigned short* xT  = (unsigned short*)(smem + 103680);  // [32][520] bf16
    unsigned int*   xTu = (unsigned int*)(smem + 103680);    // [32][260]
    float* gbuf = (float*)(smem + 136960);                   // [32][68] f32
    const int lb = blk - B_;
    const int ds = lb & 31, g32 = (lb >> 5) << 5;

    for (int idx = tid; idx < 64 * 640; idx += NTHR) {       // W1 slice
      int r = idx / 640, k = idx - r * 640;
      int grow = (r & 3) * 512 + ds * 16 + (r >> 2);
      float wv = (k < 128) ? P.W_ih1[grow * 384 + 256 + k]
                           : P.W_hh1[grow * 512 + (k - 128)];
      W1l[r * 648 + k] = f2bf(wv);
    }
    for (int idx = tid; idx < 16 * 640; idx += NTHR) {       // W2 slice
      int r = idx / 640, k = idx - r * 640;
      int grow = (r & 3) * 128 + ds * 4 + (r >> 2);
      float wv = (k < 512) ? P.W_ih2[grow * 512 + k]
                           : P.W_hh2[grow * 128 + (k - 512)];
      W2l[r * 648 + k] = f2bf(wv);
    }
    float c1 = 0.0f;                   // cell1: thread (b=tid>>4, d=tid&15)
    float c2 = 0.0f;                   // cell2: thread (b=tid>>2, d=tid&3), tid<128
    float bi2[4];
    {
      const int dloc = tid & 3;
      #pragma unroll
      for (int gq = 0; gq < 4; ++gq) {
        const int grow = gq * 128 + ds * 4 + dloc;
        bi2[gq] = P.b_ih2[grow] + P.b_hh2[grow];
      }
    }
    __syncthreads();

    const int mt = w & 1, nt = w >> 1;
    const int lr = lane & 15, lk = lane >> 4;

    for (int t = 0; t < L_; ++t) {
      const int p = t & 1, np = p ^ 1;
      // ---- waitAB: mates h1Flag>=t AND h2Flag>=t ----
      if (tid < 64) {
        const int idx = (tid < 32) ? (g32 + tid) : (256 + g32 + (tid - 32));
        while (true) {
          int v = __hip_atomic_load(&P.flags[idx], __ATOMIC_RELAXED, __HIP_MEMORY_SCOPE_AGENT);
          if (__all(v >= t)) break;
          __builtin_amdgcn_s_sleep(1);
        }
      }
      __syncthreads();

      // ======== G2s: acc2 = W2[:,512:640] @ h2[t-1]  (register A, off-path) ====
      float4v acc2 = {0.0f, 0.0f, 0.0f, 0.0f};
      if (w < 2) {
        const int arow = (g32 + w * 16 + lr) * 64 + lk * 4;
        const unsigned int* Sh = P.H2hi + p * (B_ * 64) + arow;
        const unsigned int* Sl = P.H2lo + p * (B_ * 64) + arow;
        #pragma unroll
        for (int ks = 0; ks < 4; ++ks) {
          union { unsigned int u[4]; short8v s; } ah, al;
          #pragma unroll
          for (int j = 0; j < 4; ++j) { ah.u[j] = aloadu(Sh + ks * 16 + j);
                                        al.u[j] = aloadu(Sl + ks * 16 + j); }
          short8v bv = *(const short8v*)(W2l + lr * 648 + 512 + lk * 8 + ks * 32);
          acc2 = mfma16(ah.s, bv, acc2);
          acc2 = mfma16(al.s, bv, acc2);
        }
      }

      // ======== G1h: acc1 = W1[:,128:640] @ h1[t-1]  (LDS tile, off-path) =====
      float4v acc1 = {0.0f, 0.0f, 0.0f, 0.0f};
      #pragma unroll 1
      for (int ph = 0; ph < 2; ++ph) {
        const unsigned int* S = (ph ? P.H1lo : P.H1hi) + p * (B_ * 256);
        for (int i = tid; i < 32 * 256; i += NTHR) {
          int bq = i >> 8, kp = i & 255;
          xTu[bq * 260 + kp] = aloadu(&S[(g32 + bq) * 256 + kp]);
        }
        __syncthreads();
        {
          const unsigned short* ap = xT + (mt * 16 + lr) * 520 + lk * 8;
          const unsigned short* bp = W1l + (nt * 16 + lr) * 648 + 128 + lk * 8;
          #pragma unroll
          for (int ks = 0; ks < 16; ++ks)
            acc1 = mfma16(*(const short8v*)(ap + ks * 32),
                          *(const short8v*)(bp + ks * 32), acc1);
        }
        __syncthreads();
      }

      // ---- waitC: ctx[t-1] arrival (critical) ----
      if (tid < 64) {
        const int idx = 128 + g32 + (tid & 31);
        while (true) {
          int v = __hip_atomic_load(&P.flags[idx], __ATOMIC_RELAXED, __HIP_MEMORY_SCOPE_AGENT);
          if (__all(v >= t)) break;
          __builtin_amdgcn_s_sleep(1);
        }
      }
      __syncthreads();
      // ======== G1c: acc1 += W1[:,0:128] @ ctx[t-1]  (register A, on-path) ====
      {
        const int arow = (g32 + mt * 16 + lr) * 64 + lk * 4;
        const unsigned int* Sh = P.CTXhi + arow;
        const unsigned int* Sl = P.CTXlo + arow;
        #pragma unroll
        for (int ks = 0; ks < 4; ++ks) {
          union { unsigned int u[4]; short8v s; } ah, al;
          #pragma unroll
          for (int j = 0; j < 4; ++j) { ah.u[j] = aloadu(Sh + ks * 16 + j);
                                        al.u[j] = aloadu(Sl + ks * 16 + j); }
          short8v bv = *(const short8v*)(W1l + (nt * 16 + lr) * 648 + lk * 8 + ks * 32);
          acc1 = mfma16(ah.s, bv, acc1);
          acc1 = mfma16(al.s, bv, acc1);
        }
      }
      {
        const int m0 = mt * 16 + lk * 4, n = nt * 16 + lr;
        #pragma unroll
        for (int j = 0; j < 4; ++j) gbuf[(m0 + j) * 68 + n] = acc1[j];
      }
      __syncthreads();
      // ---- cell1 -> publish h1[t] ----
      {
        const int bq = tid >> 4, d = tid & 15, gb = g32 + bq;
        float4 gv = *(const float4*)&gbuf[bq * 68 + 4 * d];
        const int ci = (t == 0) ? NVOC : P.y[gb * L_ + (t - 1)];
        const int dg = ds * 16 + d;
        const float* tb = P.table + ci * 2048 + dg;
        float gi = gv.x + tb[0];
        float gf = gv.y + tb[512];
        float gg = gv.z + tb[1024];
        float go = gv.w + tb[1536];
        float cn = sigm(gf) * c1 + sigm(gi) * tanhh(gg);
        float hn = sigm(go) * tanhh(cn);
        c1 = cn;
        float hnp = __shfl_xor(hn, 1);
        if (!(d & 1)) {
          unsigned short h0 = f2bf(hn),  l0 = f2bf(hn - bf2f(h0));
          unsigned short h1v = f2bf(hnp), l1 = f2bf(hnp - bf2f(h1v));
          astoreu(&P.H1hi[np * (B_ * 256) + gb * 256 + ds * 8 + (d >> 1)],
                  (unsigned int)h0 | ((unsigned int)h1v << 16));
          astoreu(&P.H1lo[np * (B_ * 256) + gb * 256 + ds * 8 + (d >> 1)],
                  (unsigned int)l0 | ((unsigned int)l1 << 16));
        }
      }
      __syncthreads();                                 // drain h1 stores
      if (tid == 0)
        __hip_atomic_store(&P.flags[lb], t + 1, __ATOMIC_RELAXED, __HIP_MEMORY_SCOPE_AGENT);
      // ---- waitD: mates h1Flag >= t+1 ----
      if (tid < 64) {
        const int idx = g32 + (tid & 31);
        while (true) {
          int v = __hip_atomic_load(&P.flags[idx], __ATOMIC_RELAXED, __HIP_MEMORY_SCOPE_AGENT);
          if (__all(v >= t + 1)) break;
          __builtin_amdgcn_s_sleep(1);
        }
      }
      __syncthreads();
      // ======== G2h: acc2 += W2[:,0:512] @ h1[t]  (LDS tile) ========
      #pragma unroll 1
      for (int ph = 0; ph < 2; ++ph) {
        const unsigned int* S = (ph ? P.H1lo : P.H1hi) + np * (B_ * 256);
        for (int i = tid; i < 32 * 256; i += NTHR) {
          int bq = i >> 8, kp = i & 255;
          xTu[bq * 260 + kp] = aloadu(&S[(g32 + bq) * 256 + kp]);
        }
        __syncthreads();
        if (w < 2) {
          const unsigned short* ap = xT + (w * 16 + lr) * 520 + lk * 8;
          const unsigned short* bp = W2l + lr * 648 + lk * 8;
          #pragma unroll
          for (int ks = 0; ks < 16; ++ks)
            acc2 = mfma16(*(const short8v*)(ap + ks * 32),
                          *(const short8v*)(bp + ks * 32), acc2);
        }
        __syncthreads();
      }
      if (w < 2) {
        const int m0 = w * 16 + lk * 4, n = lr;
        #pragma unroll
        for (int j = 0; j < 4; ++j) gbuf[(m0 + j) * 68 + n] = acc2[j];
      }
      __syncthreads();
      // ---- cell2 -> publish h2[t], qstore ----
      if (tid < 128) {
        const int bq = tid >> 2, dloc = tid & 3, gb = g32 + bq;
        float4 gv = *(const float4*)&gbuf[bq * 68 + 4 * dloc];
        float gi = gv.x + bi2[0];
        float gf = gv.y + bi2[1];
        float gg = gv.z + bi2[2];
        float go = gv.w + bi2[3];
        float cn = sigm(gf) * c2 + sigm(gi) * tanhh(gg);
        float hn = sigm(go) * tanhh(cn);
        c2 = cn;
        P.qstore[((size_t)t * B_ + gb) * KV_ + ds * 4 + dloc] = hn;
        float hnp = __shfl_xor(hn, 1);
        if (!(dloc & 1)) {
          unsigned short h0 = f2bf(hn),  l0 = f2bf(hn - bf2f(h0));
          unsigned short h1v = f2bf(hnp), l1 = f2bf(hnp - bf2f(h1v));
          astoreu(&P.H2hi[np * (B_ * 64) + gb * 64 + ds * 2 + (dloc >> 1)],
                  (unsigned int)h0 | ((unsigned int)h1v << 16));
          astoreu(&P.H2lo[np * (B_ * 64) + gb * 64 + ds * 2 + (dloc >> 1)],
                  (unsigned int)l0 | ((unsigned int)l1 << 16));
        }
      }
      __syncthreads();                                 // drain h2 stores
      if (tid == 0)
        __hip_atomic_store(&P.flags[256 + lb], t + 1, __ATOMIC_RELAXED, __HIP_MEMORY_SCOPE_AGENT);
    }
  }
}

// ---------------------------------------------------------------------------
// tail: predictions[b][t][v] = [q,ctx] @ emb_W.T + out_b   (fully parallel)
// ---------------------------------------------------------------------------
__global__ void pred_tail(const float* __restrict__ qstore, const float* __restrict__ ctxstore,
                          const float* __restrict__ emb_W, const float* __restrict__ out_b,
                          float* __restrict__ preds) {
  int o = blockIdx.x * 256 + threadIdx.x;
  if (o >= NPRED) return;
  int v = o % NVOC;
  int bt = o / NVOC;
  int b = bt >> 8, t = bt & 255;
  const float* q  = qstore   + ((size_t)t * B_ + b) * KV_;
  const float* cx = ctxstore + ((size_t)t * B_ + b) * KV_;
  const float* er = emb_W + v * 256;
  float acc = out_b[v];
  #pragma unroll 4
  for (int e = 0; e < 128; ++e) acc += q[e] * er[e] + cx[e] * er[128 + e];
  preds[o] = acc;
}

extern "C" void kernel_launch(void* const* d_in, const int* in_sizes, int n_in,
                              void* d_out, int out_size, void* d_ws, size_t ws_size,
                              hipStream_t stream) {
  const float* key    = (const float*)d_in[0];
  const float* value  = (const float*)d_in[1];
  const int*   enclen = (const int*)d_in[2];
  const int*   y      = (const int*)d_in[3];
  const float* emb_W  = (const float*)d_in[4];
  const float* W_ih1  = (const float*)d_in[5];
  const float* W_hh1  = (const float*)d_in[6];
  const float* b_ih1  = (const float*)d_in[7];
  const float* b_hh1  = (const float*)d_in[8];
  const float* W_ih2  = (const float*)d_in[9];
  const float* W_hh2  = (const float*)d_in[10];
  const float* b_ih2  = (const float*)d_in[11];
  const float* b_hh2  = (const float*)d_in[12];
  const float* out_b  = (const float*)d_in[13];

  float* f = (float*)d_ws;
  float* table = f;                        f += 31 * 2048;
  unsigned int* keyTp = (unsigned int*)f;  f += B_ * 64 * T_;
  unsigned int* H1hi = (unsigned int*)f;   f += 2 * B_ * 256;   // zero-region start
  unsigned int* H1lo = (unsigned int*)f;   f += 2 * B_ * 256;
  unsigned int* H2hi = (unsigned int*)f;   f += 2 * B_ * 64;
  unsigned int* H2lo = (unsigned int*)f;   f += 2 * B_ * 64;
  unsigned int* CTXhi = (unsigned int*)f;  f += B_ * 64;
  unsigned int* CTXlo = (unsigned int*)f;  f += B_ * 64;
  int*   flags = (int*)f;                  f += 384;
  float* qstore   = f;                     f += (size_t)L_ * B_ * KV_;
  float* ctxstore = f;                     f += (size_t)L_ * B_ * KV_;

  float* preds    = (float*)d_out;
  float* attn_out = preds + NPRED;

  prep_kernel<<<4096, 256, 0, stream>>>(key, emb_W, W_ih1, b_ih1, b_hh1,
                                        table, keyTp, (float*)H1hi);

  DecParams P{ y, enclen, W_ih1, W_hh1, W_ih2, W_hh2, b_ih2, b_hh2,
               table, keyTp, value, H1hi, H1lo, H2hi, H2lo, CTXhi, CTXlo,
               qstore, ctxstore, attn_out, flags };
  void* kargs[] = { (void*)&P };
  hipLaunchCooperativeKernel((void*)decoder_main, dim3(256), dim3(NTHR), kargs, 0, stream);

  pred_tail<<<(NPRED + 255) / 256, 256, 0, stream>>>(qstore, ctxstore, emb_W, out_b, preds);
}

// Round 9
// 4797.113 us; speedup vs baseline: 7.0389x; 1.5188x over previous
//
#include <hip/hip_runtime.h>

#define B_   128
#define T_   512
#define KV_  128
#define H1_  512
#define L_   256
#define NVOC 30
#define NPRED (B_*L_*NVOC)
#define NTHR 512

typedef __attribute__((ext_vector_type(8))) short short8v;
typedef __attribute__((ext_vector_type(4))) float float4v;

__device__ __forceinline__ float bf2f(unsigned short u) {
  union { unsigned int u; float f; } c; c.u = ((unsigned int)u) << 16; return c.f;
}
__device__ __forceinline__ unsigned short f2bf(float f) {
  union { float f; unsigned int u; } c; c.f = f;
  unsigned int r = (c.u + 0x7fffu + ((c.u >> 16) & 1u)) >> 16;
  return (unsigned short)r;
}
// pack f32 -> (hi bf16 low16, lo bf16 high16)
__device__ __forceinline__ unsigned int packhl(float x) {
  unsigned short hi = f2bf(x);
  unsigned short lo = f2bf(x - bf2f(hi));
  return (unsigned int)hi | ((unsigned int)lo << 16);
}
__device__ __forceinline__ float sigm(float x) { return 1.0f / (1.0f + __expf(-x)); }
__device__ __forceinline__ float tanhh(float x) { return 1.0f - 2.0f / (1.0f + __expf(2.0f * x)); }

// agent-scope point-coherent load/store (no cache-wide fences)
__device__ __forceinline__ unsigned int aloadu(const unsigned int* p) {
  return __hip_atomic_load((unsigned int*)p, __ATOMIC_RELAXED, __HIP_MEMORY_SCOPE_AGENT);
}
__device__ __forceinline__ void astoreu(unsigned int* p, unsigned int v) {
  __hip_atomic_store(p, v, __ATOMIC_RELAXED, __HIP_MEMORY_SCOPE_AGENT);
}
__device__ __forceinline__ float4v mfma16(short8v a, short8v b, float4v c) {
  return __builtin_amdgcn_mfma_f32_16x16x32_bf16(a, b, c, 0, 0, 0);
}

struct DecParams {
  const int* y; const int* enc_len;
  const float* W_ih1; const float* W_hh1;
  const float* W_ih2; const float* W_hh2;
  const float* b_ih2; const float* b_hh2;
  const float* table; const unsigned int* keyRM; const float* value;
  unsigned int* H1hi; unsigned int* H1lo;   // [2][128][256] bf16x2 (dim pairs)
  unsigned int* H2hi; unsigned int* H2lo;   // [2][128][64]
  unsigned int* CTXhi; unsigned int* CTXlo; // [128][64]
  float* qstore; float* ctxstore; float* attn_out;
  int* flags;   // [0..127] h1Flag(lb), [128..255] ctxFlag(b), [256..383] h2Flag(lb)
};

// ---------------------------------------------------------------------------
// prep: emb-gate table, swizzled row-major bf16 key, zero state+flags
// keyRM[b][t][dp'] uint (dp' = dp ^ ((t&7)<<2)) -> MFMA A-frag ds_read_b128
// lands 2-way-max bank pattern (G4 XOR swizzle).
// ---------------------------------------------------------------------------
__global__ void prep_kernel(const float* __restrict__ key,
                            const float* __restrict__ emb_W, const float* __restrict__ W_ih1,
                            const float* __restrict__ b_ih1, const float* __restrict__ b_hh1,
                            float* __restrict__ table, unsigned int* __restrict__ keyRM,
                            float* __restrict__ zbase) {
  const int NT_TAB = 31 * 2048;
  const int NT_KEY = B_ * T_ * 64;                       // 4194304 uints
  const int NT_ZER = 2*(2*B_*256) + 2*(2*B_*64) + 2*(B_*64) + 384;
  const int total = NT_TAB + NT_KEY + NT_ZER;
  for (int i = blockIdx.x * blockDim.x + threadIdx.x; i < total;
       i += gridDim.x * blockDim.x) {
    if (i < NT_TAB) {
      int row = i & 2047, v = i >> 11;
      float acc = b_ih1[row] + b_hh1[row];
      if (v < NVOC) {
        const float* e = emb_W + v * 256;
        const float* w = W_ih1 + row * 384;
        #pragma unroll 4
        for (int k = 0; k < 256; ++k) acc += e[k] * w[k];
      }
      table[v * 2048 + row] = acc;
    } else if (i < NT_TAB + NT_KEY) {
      int j = i - NT_TAB;
      int dp = j & 63, r = j >> 6;        // r = b*512 + t
      int tt = r & 511, b = r >> 9;
      int src = (b * T_ + tt) * KV_ + 2 * dp;
      unsigned int lo = f2bf(key[src]), hi = f2bf(key[src + 1]);
      keyRM[(r << 6) + (dp ^ ((tt & 7) << 2))] = lo | (hi << 16);
    } else {
      zbase[i - NT_TAB - NT_KEY] = 0.0f;
    }
  }
}

// ---------------------------------------------------------------------------
// persistent kernel, split-K flag pipeline, MFMA everywhere:
//   blocks   0..127 ("att") : batch b. MFMA attention: K swizzled in LDS
//                             (128KB), V as MFMA B-frags in VGPRs, q as hi/lo
//                             B-frags (4 per half, one per K-step) direct
//                             from H2hi/H2lo (no LDS staging).
//   blocks 128..255 ("lstm"): group g32, slice ds. W1/W2 bf16 in LDS.
//     G1h/G2h staging pipelined: all hi+lo loads issued once (regs), then
//     write-hi/mfma-hi/write-lo/mfma-lo (one L3 latency instead of two).
// ---------------------------------------------------------------------------
__global__ void __launch_bounds__(NTHR) decoder_main(DecParams P) {
  __shared__ __align__(16) unsigned char smem[145664];
  const int blk = blockIdx.x, tid = threadIdx.x;
  const int lane = tid & 63, w = tid >> 6;
  const int lr = lane & 15, lk = lane >> 4;

  if (blk < B_) {
    // ======================= att role: MFMA attention =======================
    // LDS: Kswz [512][128] bf16 swizzled (131072 B) | e_as f32[512] | a_hl u32[512] | red f32[16]
    float* e_as = (float*)(smem + 131072);
    unsigned int* a_hl = (unsigned int*)(smem + 133120);
    float* red  = (float*)(smem + 135168);
    const int b = blk, g32 = b & ~31;

    { const uint4* src = (const uint4*)(P.keyRM + (size_t)b * (T_ * 64));
      uint4* dst = (uint4*)smem;
      for (int i = tid; i < (T_ * 64) / 4; i += NTHR) dst[i] = src[i]; }
    // V as PV B-frags: lane holds V[t=ks*32+lk*8+j][d=w*16+lr], j=0..7
    short8v vfragv[16];
    { const float* vb = P.value + (size_t)b * T_ * KV_ + (w * 16 + lr);
      #pragma unroll
      for (int ks = 0; ks < 16; ++ks) {
        union { unsigned short us[8]; short8v s; } tv;
        #pragma unroll
        for (int j = 0; j < 8; ++j) tv.us[j] = f2bf(vb[(ks * 32 + lk * 8 + j) * KV_]);
        vfragv[ks] = tv.s;
      } }
    const int len = P.enc_len[b];
    const float SCALE = 0.08838834764831845f;          // 1/sqrt(128)
    __syncthreads();

    for (int t = 0; t < L_; ++t) {
      const int np = (t & 1) ^ 1;
      // ---- wait h2[t] ----
      if (tid < 64) {
        const int idx = 256 + g32 + (tid & 31);
        while (true) {
          int v = __hip_atomic_load(&P.flags[idx], __ATOMIC_RELAXED, __HIP_MEMORY_SCOPE_AGENT);
          if (__all(v >= t + 1)) break;
          __builtin_amdgcn_s_sleep(1);
        }
      }
      __syncthreads();
      // ---- q B-frags (hi/lo), ONE PER K-STEP: dims = ks*32 + lk*8 + j ----
      union frag_t { unsigned int u[4]; short8v s; };
      frag_t qh[4], ql[4];
      { const unsigned int* Hh = P.H2hi + np * (B_ * 64) + b * 64;
        const unsigned int* Hl = P.H2lo + np * (B_ * 64) + b * 64;
        #pragma unroll
        for (int ks = 0; ks < 4; ++ks)
          #pragma unroll
          for (int jj = 0; jj < 4; ++jj) {
            qh[ks].u[jj] = aloadu(Hh + ks * 16 + lk * 4 + jj);
            ql[ks].u[jj] = aloadu(Hl + ks * 16 + lk * 4 + jj);
          } }
      // ---- energy: e[t] = K @ q via MFMA (A=K rows=t, B=q) ----
      #pragma unroll
      for (int i = 0; i < 4; ++i) {
        const int t0 = (w * 4 + i) * 16;
        const int tloc = t0 + lr;
        const unsigned char* rowp = smem + tloc * 256;
        const int sw = (tloc & 7) << 4;
        float4v acc = {0.0f, 0.0f, 0.0f, 0.0f};
        #pragma unroll
        for (int ks = 0; ks < 4; ++ks) {
          short8v av = *(const short8v*)(rowp + ((ks * 64 + lk * 16) ^ sw));
          acc = mfma16(av, qh[ks].s, acc);
          acc = mfma16(av, ql[ks].s, acc);
        }
        if (lr == 0) {
          #pragma unroll
          for (int j2 = 0; j2 < 4; ++j2) e_as[t0 + lk * 4 + j2] = acc[j2];
        }
      }
      __syncthreads();
      // ---- softmax over T ----
      float e = (tid < len) ? e_as[tid] * SCALE : -8.8388348e7f;  // (-1e9)*scale
      float m = e;
      #pragma unroll
      for (int off = 32; off > 0; off >>= 1) m = fmaxf(m, __shfl_xor(m, off));
      if (lane == 0) red[w] = m;
      __syncthreads();
      float M = red[0];
      #pragma unroll
      for (int i2 = 1; i2 < 8; ++i2) M = fmaxf(M, red[i2]);
      float pe = __expf(e - M);
      float s = pe;
      #pragma unroll
      for (int off = 32; off > 0; off >>= 1) s += __shfl_xor(s, off);
      if (lane == 0) red[8 + w] = s;
      a_hl[tid] = packhl(pe);
      __syncthreads();
      float S = 0.0f;
      #pragma unroll
      for (int i2 = 0; i2 < 8; ++i2) S += red[8 + i2];
      const float invS = 1.0f / S;
      // ---- PV: ctx = a @ V via MFMA (A=a hi/lo, B=V regs); full K per wave ----
      float4v acc0 = {0.0f, 0.0f, 0.0f, 0.0f};
      float4v acc1 = {0.0f, 0.0f, 0.0f, 0.0f};
      #pragma unroll
      for (int ks = 0; ks < 16; ++ks) {
        const unsigned int* ap = a_hl + ks * 32 + lk * 8;
        uint4 ua = *(const uint4*)(ap);
        uint4 ub = *(const uint4*)(ap + 4);
        union { unsigned short us[8]; short8v s; } ah, al;
        ah.us[0] = (unsigned short)ua.x;  al.us[0] = (unsigned short)(ua.x >> 16);
        ah.us[1] = (unsigned short)ua.y;  al.us[1] = (unsigned short)(ua.y >> 16);
        ah.us[2] = (unsigned short)ua.z;  al.us[2] = (unsigned short)(ua.z >> 16);
        ah.us[3] = (unsigned short)ua.w;  al.us[3] = (unsigned short)(ua.w >> 16);
        ah.us[4] = (unsigned short)ub.x;  al.us[4] = (unsigned short)(ub.x >> 16);
        ah.us[5] = (unsigned short)ub.y;  al.us[5] = (unsigned short)(ub.y >> 16);
        ah.us[6] = (unsigned short)ub.z;  al.us[6] = (unsigned short)(ub.z >> 16);
        ah.us[7] = (unsigned short)ub.w;  al.us[7] = (unsigned short)(ub.w >> 16);
        acc0 = mfma16(ah.s, vfragv[ks], acc0);
        acc1 = mfma16(al.s, vfragv[ks], acc1);
      }
      float cv = (acc0[0] + acc1[0]) * invS;           // D row0 at lanes 0..15
      float cvp = __shfl_xor(cv, 1);
      if (lane < 16) {
        const int d = w * 16 + lane;
        P.ctxstore[((size_t)t * B_ + b) * KV_ + d] = cv;
        if (!(lane & 1)) {
          unsigned short h0 = f2bf(cv),  l0 = f2bf(cv - bf2f(h0));
          unsigned short h1v = f2bf(cvp), l1 = f2bf(cvp - bf2f(h1v));
          astoreu(&P.CTXhi[b * 64 + (d >> 1)], (unsigned int)h0 | ((unsigned int)h1v << 16));
          astoreu(&P.CTXlo[b * 64 + (d >> 1)], (unsigned int)l0 | ((unsigned int)l1 << 16));
        }
      }
      if (b == 0) P.attn_out[t * T_ + tid] = pe * invS;
      __syncthreads();                                 // drain stores
      if (tid == 0)
        __hip_atomic_store(&P.flags[128 + b], t + 1, __ATOMIC_RELAXED, __HIP_MEMORY_SCOPE_AGENT);
    }
  } else {
    // ================= lstm role: LSTM1 + LSTM2 slices (MFMA) =================
    unsigned short* W1l = (unsigned short*)smem;             // [64][648] bf16
    unsigned short* W2l = (unsigned short*)(smem + 82944);   // [16][648] bf16
    unsigned short* xT  = (unsigned short*)(smem + 103680);  // [32][520] bf16
    unsigned int*   xTu = (unsigned int*)(smem + 103680);    // [32][260]
    float* gbuf = (float*)(smem + 136960);                   // [32][68] f32
    const int lb = blk - B_;
    const int ds = lb & 31, g32 = (lb >> 5) << 5;

    for (int idx = tid; idx < 64 * 640; idx += NTHR) {       // W1 slice
      int r = idx / 640, k = idx - r * 640;
      int grow = (r & 3) * 512 + ds * 16 + (r >> 2);
      float wv = (k < 128) ? P.W_ih1[grow * 384 + 256 + k]
                           : P.W_hh1[grow * 512 + (k - 128)];
      W1l[r * 648 + k] = f2bf(wv);
    }
    for (int idx = tid; idx < 16 * 640; idx += NTHR) {       // W2 slice
      int r = idx / 640, k = idx - r * 640;
      int grow = (r & 3) * 128 + ds * 4 + (r >> 2);
      float wv = (k < 512) ? P.W_ih2[grow * 512 + k]
                           : P.W_hh2[grow * 128 + (k - 512)];
      W2l[r * 648 + k] = f2bf(wv);
    }
    float c1 = 0.0f;                   // cell1: thread (b=tid>>4, d=tid&15)
    float c2 = 0.0f;                   // cell2: thread (b=tid>>2, d=tid&3), tid<128
    float bi2[4];
    {
      const int dloc = tid & 3;
      #pragma unroll
      for (int gq = 0; gq < 4; ++gq) {
        const int grow = gq * 128 + ds * 4 + dloc;
        bi2[gq] = P.b_ih2[grow] + P.b_hh2[grow];
      }
    }
    __syncthreads();

    const int mt = w & 1, nt = w >> 1;

    for (int t = 0; t < L_; ++t) {
      const int p = t & 1, np = p ^ 1;
      // ---- waitAB: mates h1Flag>=t AND h2Flag>=t ----
      if (tid < 64) {
        const int idx = (tid < 32) ? (g32 + tid) : (256 + g32 + (tid - 32));
        while (true) {
          int v = __hip_atomic_load(&P.flags[idx], __ATOMIC_RELAXED, __HIP_MEMORY_SCOPE_AGENT);
          if (__all(v >= t)) break;
          __builtin_amdgcn_s_sleep(1);
        }
      }
      __syncthreads();

      // ---- prefetch h1[t-1] hi+lo (32 loads in flight, one L3 latency) ----
      unsigned int rh[16], rl[16];
      {
        const unsigned int* Sh = P.H1hi + p * (B_ * 256);
        const unsigned int* Sl = P.H1lo + p * (B_ * 256);
        #pragma unroll
        for (int ii = 0; ii < 16; ++ii) {
          int i = tid + ii * NTHR; int bq = i >> 8, kp = i & 255;
          int off = (g32 + bq) * 256 + kp;
          rh[ii] = aloadu(Sh + off);
          rl[ii] = aloadu(Sl + off);
        }
      }

      // ======== G2s: acc2 = W2[:,512:640] @ h2[t-1]  (register A, off-path) ====
      float4v acc2 = {0.0f, 0.0f, 0.0f, 0.0f};
      if (w < 2) {
        const int arow = (g32 + w * 16 + lr) * 64 + lk * 4;
        const unsigned int* Sh = P.H2hi + p * (B_ * 64) + arow;
        const unsigned int* Sl = P.H2lo + p * (B_ * 64) + arow;
        #pragma unroll
        for (int ks = 0; ks < 4; ++ks) {
          union { unsigned int u[4]; short8v s; } ah, al;
          #pragma unroll
          for (int j = 0; j < 4; ++j) { ah.u[j] = aloadu(Sh + ks * 16 + j);
                                        al.u[j] = aloadu(Sl + ks * 16 + j); }
          short8v bv = *(const short8v*)(W2l + lr * 648 + 512 + lk * 8 + ks * 32);
          acc2 = mfma16(ah.s, bv, acc2);
          acc2 = mfma16(al.s, bv, acc2);
        }
      }

      // ======== G1h: acc1 = W1[:,128:640] @ h1[t-1]  (pipelined hi/lo) =====
      float4v acc1 = {0.0f, 0.0f, 0.0f, 0.0f};
      #pragma unroll
      for (int ii = 0; ii < 16; ++ii) {
        int i = tid + ii * NTHR; xTu[(i >> 8) * 260 + (i & 255)] = rh[ii];
      }
      __syncthreads();
      {
        const unsigned short* ap = xT + (mt * 16 + lr) * 520 + lk * 8;
        const unsigned short* bp = W1l + (nt * 16 + lr) * 648 + 128 + lk * 8;
        #pragma unroll
        for (int ks = 0; ks < 16; ++ks)
          acc1 = mfma16(*(const short8v*)(ap + ks * 32),
                        *(const short8v*)(bp + ks * 32), acc1);
      }
      __syncthreads();
      #pragma unroll
      for (int ii = 0; ii < 16; ++ii) {
        int i = tid + ii * NTHR; xTu[(i >> 8) * 260 + (i & 255)] = rl[ii];
      }
      __syncthreads();
      {
        const unsigned short* ap = xT + (mt * 16 + lr) * 520 + lk * 8;
        const unsigned short* bp = W1l + (nt * 16 + lr) * 648 + 128 + lk * 8;
        #pragma unroll
        for (int ks = 0; ks < 16; ++ks)
          acc1 = mfma16(*(const short8v*)(ap + ks * 32),
                        *(const short8v*)(bp + ks * 32), acc1);
      }

      // ---- waitC: ctx[t-1] arrival (critical) ----
      if (tid < 64) {
        const int idx = 128 + g32 + (tid & 31);
        while (true) {
          int v = __hip_atomic_load(&P.flags[idx], __ATOMIC_RELAXED, __HIP_MEMORY_SCOPE_AGENT);
          if (__all(v >= t)) break;
          __builtin_amdgcn_s_sleep(1);
        }
      }
      __syncthreads();
      // ======== G1c: acc1 += W1[:,0:128] @ ctx[t-1]  (register A, on-path) ====
      {
        const int arow = (g32 + mt * 16 + lr) * 64 + lk * 4;
        const unsigned int* Sh = P.CTXhi + arow;
        const unsigned int* Sl = P.CTXlo + arow;
        #pragma unroll
        for (int ks = 0; ks < 4; ++ks) {
          union { unsigned int u[4]; short8v s; } ah, al;
          #pragma unroll
          for (int j = 0; j < 4; ++j) { ah.u[j] = aloadu(Sh + ks * 16 + j);
                                        al.u[j] = aloadu(Sl + ks * 16 + j); }
          short8v bv = *(const short8v*)(W1l + (nt * 16 + lr) * 648 + lk * 8 + ks * 32);
          acc1 = mfma16(ah.s, bv, acc1);
          acc1 = mfma16(al.s, bv, acc1);
        }
      }
      {
        const int m0 = mt * 16 + lk * 4, n = nt * 16 + lr;
        #pragma unroll
        for (int j = 0; j < 4; ++j) gbuf[(m0 + j) * 68 + n] = acc1[j];
      }
      __syncthreads();
      // ---- cell1 -> publish h1[t] ----
      {
        const int bq = tid >> 4, d = tid & 15, gb = g32 + bq;
        float4 gv = *(const float4*)&gbuf[bq * 68 + 4 * d];
        const int ci = (t == 0) ? NVOC : P.y[gb * L_ + (t - 1)];
        const int dg = ds * 16 + d;
        const float* tb = P.table + ci * 2048 + dg;
        float gi = gv.x + tb[0];
        float gf = gv.y + tb[512];
        float gg = gv.z + tb[1024];
        float go = gv.w + tb[1536];
        float cn = sigm(gf) * c1 + sigm(gi) * tanhh(gg);
        float hn = sigm(go) * tanhh(cn);
        c1 = cn;
        float hnp = __shfl_xor(hn, 1);
        if (!(d & 1)) {
          unsigned short h0 = f2bf(hn),  l0 = f2bf(hn - bf2f(h0));
          unsigned short h1v = f2bf(hnp), l1 = f2bf(hnp - bf2f(h1v));
          astoreu(&P.H1hi[np * (B_ * 256) + gb * 256 + ds * 8 + (d >> 1)],
                  (unsigned int)h0 | ((unsigned int)h1v << 16));
          astoreu(&P.H1lo[np * (B_ * 256) + gb * 256 + ds * 8 + (d >> 1)],
                  (unsigned int)l0 | ((unsigned int)l1 << 16));
        }
      }
      __syncthreads();                                 // drain h1 stores
      if (tid == 0)
        __hip_atomic_store(&P.flags[lb], t + 1, __ATOMIC_RELAXED, __HIP_MEMORY_SCOPE_AGENT);
      // ---- waitD: mates h1Flag >= t+1 ----
      if (tid < 64) {
        const int idx = g32 + (tid & 31);
        while (true) {
          int v = __hip_atomic_load(&P.flags[idx], __ATOMIC_RELAXED, __HIP_MEMORY_SCOPE_AGENT);
          if (__all(v >= t + 1)) break;
          __builtin_amdgcn_s_sleep(1);
        }
      }
      __syncthreads();
      // ======== G2h: acc2 += W2[:,0:512] @ h1[t]  (pipelined hi/lo) ========
      {
        const unsigned int* Sh = P.H1hi + np * (B_ * 256);
        const unsigned int* Sl = P.H1lo + np * (B_ * 256);
        #pragma unroll
        for (int ii = 0; ii < 16; ++ii) {
          int i = tid + ii * NTHR; int bq = i >> 8, kp = i & 255;
          int off = (g32 + bq) * 256 + kp;
          rh[ii] = aloadu(Sh + off);
          rl[ii] = aloadu(Sl + off);
        }
      }
      #pragma unroll
      for (int ii = 0; ii < 16; ++ii) {
        int i = tid + ii * NTHR; xTu[(i >> 8) * 260 + (i & 255)] = rh[ii];
      }
      __syncthreads();
      if (w < 2) {
        const unsigned short* ap = xT + (w * 16 + lr) * 520 + lk * 8;
        const unsigned short* bp = W2l + lr * 648 + lk * 8;
        #pragma unroll
        for (int ks = 0; ks < 16; ++ks)
          acc2 = mfma16(*(const short8v*)(ap + ks * 32),
                        *(const short8v*)(bp + ks * 32), acc2);
      }
      __syncthreads();
      #pragma unroll
      for (int ii = 0; ii < 16; ++ii) {
        int i = tid + ii * NTHR; xTu[(i >> 8) * 260 + (i & 255)] = rl[ii];
      }
      __syncthreads();
      if (w < 2) {
        const unsigned short* ap = xT + (w * 16 + lr) * 520 + lk * 8;
        const unsigned short* bp = W2l + lr * 648 + lk * 8;
        #pragma unroll
        for (int ks = 0; ks < 16; ++ks)
          acc2 = mfma16(*(const short8v*)(ap + ks * 32),
                        *(const short8v*)(bp + ks * 32), acc2);
        const int m0 = w * 16 + lk * 4, n = lr;
        #pragma unroll
        for (int j = 0; j < 4; ++j) gbuf[(m0 + j) * 68 + n] = acc2[j];
      }
      __syncthreads();
      // ---- cell2 -> publish h2[t], qstore ----
      if (tid < 128) {
        const int bq = tid >> 2, dloc = tid & 3, gb = g32 + bq;
        float4 gv = *(const float4*)&gbuf[bq * 68 + 4 * dloc];
        float gi = gv.x + bi2[0];
        float gf = gv.y + bi2[1];
        float gg = gv.z + bi2[2];
        float go = gv.w + bi2[3];
        float cn = sigm(gf) * c2 + sigm(gi) * tanhh(gg);
        float hn = sigm(go) * tanhh(cn);
        c2 = cn;
        P.qstore[((size_t)t * B_ + gb) * KV_ + ds * 4 + dloc] = hn;
        float hnp = __shfl_xor(hn, 1);
        if (!(dloc & 1)) {
          unsigned short h0 = f2bf(hn),  l0 = f2bf(hn - bf2f(h0));
          unsigned short h1v = f2bf(hnp), l1 = f2bf(hnp - bf2f(h1v));
          astoreu(&P.H2hi[np * (B_ * 64) + gb * 64 + ds * 2 + (dloc >> 1)],
                  (unsigned int)h0 | ((unsigned int)h1v << 16));
          astoreu(&P.H2lo[np * (B_ * 64) + gb * 64 + ds * 2 + (dloc >> 1)],
                  (unsigned int)l0 | ((unsigned int)l1 << 16));
        }
      }
      __syncthreads();                                 // drain h2 stores
      if (tid == 0)
        __hip_atomic_store(&P.flags[256 + lb], t + 1, __ATOMIC_RELAXED, __HIP_MEMORY_SCOPE_AGENT);
    }
  }
}

// ---------------------------------------------------------------------------
// tail: predictions[b][t][v] = [q,ctx] @ emb_W.T + out_b   (fully parallel)
// ---------------------------------------------------------------------------
__global__ void pred_tail(const float* __restrict__ qstore, const float* __restrict__ ctxstore,
                          const float* __restrict__ emb_W, const float* __restrict__ out_b,
                          float* __restrict__ preds) {
  int o = blockIdx.x * 256 + threadIdx.x;
  if (o >= NPRED) return;
  int v = o % NVOC;
  int bt = o / NVOC;
  int b = bt >> 8, t = bt & 255;
  const float* q  = qstore   + ((size_t)t * B_ + b) * KV_;
  const float* cx = ctxstore + ((size_t)t * B_ + b) * KV_;
  const float* er = emb_W + v * 256;
  float acc = out_b[v];
  #pragma unroll 4
  for (int e = 0; e < 128; ++e) acc += q[e] * er[e] + cx[e] * er[128 + e];
  preds[o] = acc;
}

extern "C" void kernel_launch(void* const* d_in, const int* in_sizes, int n_in,
                              void* d_out, int out_size, void* d_ws, size_t ws_size,
                              hipStream_t stream) {
  const float* key    = (const float*)d_in[0];
  const float* value  = (const float*)d_in[1];
  const int*   enclen = (const int*)d_in[2];
  const int*   y      = (const int*)d_in[3];
  const float* emb_W  = (const float*)d_in[4];
  const float* W_ih1  = (const float*)d_in[5];
  const float* W_hh1  = (const float*)d_in[6];
  const float* b_ih1  = (const float*)d_in[7];
  const float* b_hh1  = (const float*)d_in[8];
  const float* W_ih2  = (const float*)d_in[9];
  const float* W_hh2  = (const float*)d_in[10];
  const float* b_ih2  = (const float*)d_in[11];
  const float* b_hh2  = (const float*)d_in[12];
  const float* out_b  = (const float*)d_in[13];

  float* f = (float*)d_ws;
  float* table = f;                        f += 31 * 2048;
  unsigned int* keyRM = (unsigned int*)f;  f += B_ * T_ * 64;
  unsigned int* H1hi = (unsigned int*)f;   f += 2 * B_ * 256;   // zero-region start
  unsigned int* H1lo = (unsigned int*)f;   f += 2 * B_ * 256;
  unsigned int* H2hi = (unsigned int*)f;   f += 2 * B_ * 64;
  unsigned int* H2lo = (unsigned int*)f;   f += 2 * B_ * 64;
  unsigned int* CTXhi = (unsigned int*)f;  f += B_ * 64;
  unsigned int* CTXlo = (unsigned int*)f;  f += B_ * 64;
  int*   flags = (int*)f;                  f += 384;
  float* qstore   = f;                     f += (size_t)L_ * B_ * KV_;
  float* ctxstore = f;                     f += (size_t)L_ * B_ * KV_;

  float* preds    = (float*)d_out;
  float* attn_out = preds + NPRED;

  prep_kernel<<<4096, 256, 0, stream>>>(key, emb_W, W_ih1, b_ih1, b_hh1,
                                        table, keyRM, (float*)H1hi);

  DecParams P{ y, enclen, W_ih1, W_hh1, W_ih2, W_hh2, b_ih2, b_hh2,
               table, keyRM, value, H1hi, H1lo, H2hi, H2lo, CTXhi, CTXlo,
               qstore, ctxstore, attn_out, flags };
  void* kargs[] = { (void*)&P };
  hipLaunchCooperativeKernel((void*)decoder_main, dim3(256), dim3(NTHR), kargs, 0, stream);

  pred_tail<<<(NPRED + 255) / 256, 256, 0, stream>>>(qstore, ctxstore, emb_W, out_b, preds);
}